// Round 16
// baseline (360.344 us; speedup 1.0000x reference)
//
#include <hip/hip_runtime.h>
#include <hip/hip_bf16.h>
#include <math.h>

typedef short bf16x8 __attribute__((ext_vector_type(8)));
typedef float f32x4 __attribute__((ext_vector_type(4)));
typedef unsigned short u16;
typedef unsigned long long u64;

#define N_TOK  4096
#define D_IN   512
#define D_ATTN 64
#define NBI    1024
#define CAPW   128
#define TOPP   0.9f
#define LN_EPS 1e-5f
#define AMAXV  (N_TOK - 1)
#define FLTMAX 3.402823466e38f
#define MSCALE 524288.0f   /* 2^19 fixed-point mass scale */

__device__ __forceinline__ u16 f2bf(float f) {
  unsigned int u = __float_as_uint(f);
  return (u16)((u + 0x7FFFu + ((u >> 16) & 1u)) >> 16);
}

__device__ __forceinline__ float bf2f(u16 v) {
  return __uint_as_float(((unsigned)v) << 16);
}

__device__ __forceinline__ unsigned mfix(float e) {
  return (unsigned)(e * MSCALE + 0.5f);
}

__device__ __forceinline__ void gload16(const u16* g, u16* l) {
  __builtin_amdgcn_global_load_lds(
      (const __attribute__((address_space(1))) unsigned int*)g,
      (__attribute__((address_space(3))) unsigned int*)l, 16, 0, 0);
}

// ---------------------------------------------------------------------------
// gemm128: C = sum_seg rowmap(A_s) @ B_s^T.  BM=128, BN=64, BK=64.
// DB = min(TOTAL, DBMAX) LDS buffers.
//   DB=3: depth-2 prefetch, counted vmcnt(6) (2 blocks/CU @72KB).
//   DB=2: depth-1 prefetch, vmcnt(0)        (3 blocks/CU @48KB).
//   DB=1: single tile.
// blockIdx.z adds K-offset z*KSEG (split-K); EPI 3/6 offset out by z*ldct.
// EPI: 0 f32; 1 tanh->bf16; 2 bf16; 3 f32 += (z-partial); 4 bf16 dual;
//      5 split col<64 tanh->Cb / col>=64 CbT; 6 f32 -> Cf + z*ldct
// ---------------------------------------------------------------------------
template<int EPI, int NSEG, int KSEG, int DBMAX = 3>
__global__ __launch_bounds__(256)
void gemm128(const u16* __restrict__ A0, int lda0, int sh0, const u16* __restrict__ B0, int ldb0,
             const u16* __restrict__ A1, int lda1, int sh1, const u16* __restrict__ B1, int ldb1,
             const u16* __restrict__ A2, int lda2, int sh2, const u16* __restrict__ B2, int ldb2,
             const u16* __restrict__ A3, int lda3, int sh3, const u16* __restrict__ B3, int ldb3,
             float* __restrict__ Cf, u16* __restrict__ Cb, u16* __restrict__ CbT,
             int ldc, int ldct)
{
  constexpr int BN = 64;
  constexpr int NF = BN / 32;
  constexpr int IPSEG = KSEG >> 6;
  constexpr int TOTAL = NSEG * IPSEG;
  constexpr int DB = (TOTAL < DBMAX) ? TOTAL : DBMAX;
  constexpr int DEPTH = (DB > 1) ? (DB - 1) : 0;

  __shared__ u16 sA[DB][128 * 64];
  __shared__ u16 sB[DB][BN * 64];

  const int tid  = threadIdx.x;
  const int wave = tid >> 6;
  const int lane = tid & 63;
  const int l15  = lane & 15;
  const int l4   = lane >> 4;
  const int brow = blockIdx.y << 7;
  const int bcol = blockIdx.x * BN;
  const int kz   = blockIdx.z * KSEG;
  const int wr64 = (wave >> 1) << 6;
  const int wcol = (wave & 1) * (BN >> 1);

  auto stage = [&](int buf, int it) {
    int seg = (NSEG == 1) ? 0 : (it / IPSEG);
    int kk  = (NSEG == 1) ? (it << 6) : ((it % IPSEG) << 6);
    const u16 *Ab, *Bb; int la, lb, sh;
    if (seg == 0)      { Ab = A0; la = lda0; sh = sh0; Bb = B0; lb = ldb0; }
    else if (seg == 1) { Ab = A1; la = lda1; sh = sh1; Bb = B1; lb = ldb1; }
    else if (seg == 2) { Ab = A2; la = lda2; sh = sh2; Bb = B2; lb = ldb2; }
    else               { Ab = A3; la = lda3; sh = sh3; Bb = B3; lb = ldb3; }
    kk += kz;
#pragma unroll
    for (int q = 0; q < 4; ++q) {              // A tile 128x64
      int idx = q * 256 + tid;
      int row = idx >> 3;
      int chunk = (idx & 7) ^ (row & 7);
      int r = brow + row + sh;
      r = (r < 0) ? 0 : ((r > AMAXV) ? AMAXV : r);
      gload16(Ab + (size_t)r * la + kk + chunk * 8, &sA[buf][idx * 8]);
    }
#pragma unroll
    for (int q = 0; q < BN / 32; ++q) {        // B tile 64x64
      int idx = q * 256 + tid;
      int row = idx >> 3;
      int chunk = (idx & 7) ^ (row & 7);
      gload16(Bb + (size_t)(bcol + row) * lb + kk + chunk * 8, &sB[buf][idx * 8]);
    }
  };

  f32x4 acc[4][NF];
#pragma unroll
  for (int m = 0; m < 4; ++m)
#pragma unroll
    for (int n = 0; n < NF; ++n) {
      acc[m][n][0] = 0.f; acc[m][n][1] = 0.f; acc[m][n][2] = 0.f; acc[m][n][3] = 0.f;
    }

  stage(0, 0);
  if (DEPTH >= 2 && TOTAL > 1) stage(1 % DB, 1);

  for (int i = 0; i < TOTAL; ++i) {
    if (DEPTH >= 2 && i + 1 < TOTAL) asm volatile("s_waitcnt vmcnt(6)" ::: "memory");
    else                             asm volatile("s_waitcnt vmcnt(0)" ::: "memory");
    __builtin_amdgcn_s_barrier();
    if (DEPTH > 0 && i + DEPTH < TOTAL) stage((i + DEPTH) % DB, i + DEPTH);
    const int c = i % DB;
#pragma unroll
    for (int ks = 0; ks < 2; ++ks) {
      bf16x8 af[4], bfr[NF];
#pragma unroll
      for (int m = 0; m < 4; ++m) {
        int ar = wr64 + m * 16 + l15;
        af[m] = *(const bf16x8*)&sA[c][ar * 64 + (((ks << 2) + l4) ^ (ar & 7)) * 8];
      }
#pragma unroll
      for (int n = 0; n < NF; ++n) {
        int br = wcol + n * 16 + l15;
        bfr[n] = *(const bf16x8*)&sB[c][br * 64 + (((ks << 2) + l4) ^ (br & 7)) * 8];
      }
#pragma unroll
      for (int m = 0; m < 4; ++m)
#pragma unroll
        for (int n = 0; n < NF; ++n)
          acc[m][n] = __builtin_amdgcn_mfma_f32_16x16x32_bf16(af[m], bfr[n], acc[m][n], 0, 0, 0);
    }
  }

  float* Cfz = (EPI == 6 || EPI == 3) ? (Cf + (size_t)blockIdx.z * (size_t)ldct) : Cf;
#pragma unroll
  for (int m = 0; m < 4; ++m)
#pragma unroll
    for (int n = 0; n < NF; ++n)
#pragma unroll
      for (int r = 0; r < 4; ++r) {
        const int row = brow + wr64 + m * 16 + l4 * 4 + r;
        const int col = bcol + wcol + n * 16 + l15;
        const float v = acc[m][n][r];
        if (EPI == 0) Cf[(size_t)row * ldc + col] = v;
        if (EPI == 1) Cb[(size_t)row * ldc + col] = f2bf(tanhf(v));
        if (EPI == 2) Cb[(size_t)row * ldc + col] = f2bf(v);
        if (EPI == 3) Cfz[(size_t)row * ldc + col] += v;
        if (EPI == 4) {
          u16 hv = f2bf(v);
          Cb [(size_t)row * ldc  + col] = hv;
          CbT[(size_t)col * ldct + row] = hv;
        }
        if (EPI == 5) {
          if (col < 64) Cb [(size_t)row * 64 + col]        = f2bf(tanhf(v));
          else          CbT[(size_t)row * 64 + (col - 64)] = f2bf(v);
        }
        if (EPI == 6) Cfz[(size_t)row * ldc + col] = v;
      }
}

// ---------------------------------------------------------------------------
// pvfix: Xa = bf16(sum of 4 split-K partials); XaT = Xa^T only if WRT.
// ---------------------------------------------------------------------------
template<bool WRT>
__global__ __launch_bounds__(256)
void pvfix(const float* __restrict__ Zp, u16* __restrict__ Xa, u16* __restrict__ XaT)
{
  const size_t st = (size_t)N_TOK * D_IN;
  __shared__ u16 tile[64][65];
  const int bx = blockIdx.x, by = blockIdx.y;
  const int t = threadIdx.x;
  const int tx = t & 15, ty = t >> 4;
#pragma unroll
  for (int i = 0; i < 4; ++i) {
    int r = by * 64 + ty + 16 * i;
    int c = bx * 64 + tx * 4;
    size_t idx = (size_t)r * D_IN + c;
    float4 a = *(const float4*)&Zp[idx];
    float4 b = *(const float4*)&Zp[idx + st];
    float4 d = *(const float4*)&Zp[idx + 2 * st];
    float4 e = *(const float4*)&Zp[idx + 3 * st];
    u16 q0 = f2bf(a.x + b.x + d.x + e.x), q1 = f2bf(a.y + b.y + d.y + e.y);
    u16 q2 = f2bf(a.z + b.z + d.z + e.z), q3 = f2bf(a.w + b.w + d.w + e.w);
    *(ushort4*)&Xa[idx] = make_ushort4(q0, q1, q2, q3);
    if (WRT) {
      tile[ty + 16 * i][tx * 4 + 0] = q0;
      tile[ty + 16 * i][tx * 4 + 1] = q1;
      tile[ty + 16 * i][tx * 4 + 2] = q2;
      tile[ty + 16 * i][tx * 4 + 3] = q3;
    }
  }
  if (WRT) {
    __syncthreads();
#pragma unroll
    for (int i = 0; i < 4; ++i) {
      int cc = ty + 16 * i;
      int rq = tx * 4;
      u16 o0 = tile[rq + 0][cc], o1 = tile[rq + 1][cc];
      u16 o2 = tile[rq + 2][cc], o3 = tile[rq + 3][cc];
      *(ushort4*)&XaT[(size_t)(bx * 64 + cc) * N_TOK + by * 64 + rq] =
          make_ushort4(o0, o1, o2, o3);
    }
  }
}

// ---------------------------------------------------------------------------
// Block-per-row nucleus (R14 structure + lev>0 guard around candidate-stats:
// level 0 skips the stats reduce entirely — tot=4096 and cmin<cmax known).
// ---------------------------------------------------------------------------
__global__ __launch_bounds__(256)
void nucleus_block(const u16* __restrict__ S, u16* __restrict__ A, int apitch)
{
  const int t = threadIdx.x;
  const int wv = t >> 6, ln = t & 63;

  __shared__ unsigned hist[4][NBI];        // 16 KB
  __shared__ float ge[CAPW];
  __shared__ int   gcol[CAPW];
  __shared__ unsigned gm[CAPW];
  __shared__ unsigned char kf[CAPW];
  __shared__ float sMin[4], sMax[4], sDen[4];
  __shared__ int   sCnt[4], sS[4];
  __shared__ unsigned sScan[4];
  __shared__ unsigned s_Ab;
  __shared__ int   s_cnt;

  for (int rr = 0; rr < 2; ++rr) {
    const int row = blockIdx.x + rr * (N_TOK / 2);
    const u16* srow = S + (size_t)row * N_TOK;
    u16* arow = A + (size_t)row * apitch;

    __syncthreads();

    float evf[16];
    float lmax = -FLTMAX, lmin = FLTMAX;
#pragma unroll
    for (int q = 0; q < 4; ++q) {
      ushort4 v = ((const ushort4*)srow)[q * 256 + t];
      float e0 = bf2f(v.x), e1 = bf2f(v.y), e2 = bf2f(v.z), e3 = bf2f(v.w);
      evf[4*q+0] = e0; evf[4*q+1] = e1; evf[4*q+2] = e2; evf[4*q+3] = e3;
      lmax = fmaxf(lmax, fmaxf(fmaxf(e0, e1), fmaxf(e2, e3)));
      lmin = fminf(lmin, fminf(fminf(e0, e1), fminf(e2, e3)));
    }
#pragma unroll
    for (int o = 32; o; o >>= 1) {
      lmax = fmaxf(lmax, __shfl_xor(lmax, o));
      lmin = fminf(lmin, __shfl_xor(lmin, o));
    }
    if (ln == 0) { sMax[wv] = lmax; sMin[wv] = lmin; }
    __syncthreads();
    const float smax = fmaxf(fmaxf(sMax[0], sMax[1]), fmaxf(sMax[2], sMax[3]));
    const float smin = fminf(fminf(sMin[0], sMin[1]), fminf(sMin[2], sMin[3]));

#pragma unroll
    for (int j = 0; j < 16; ++j) evf[j] = __expf(evf[j] - smax);

    unsigned keepM = 0, cand = 0xFFFFu;
    unsigned Agt = 0, T = 0;
    bool haveT = false;
    float lo = __expf(smin - smax);
    float width = fmaxf(1.0f - lo, 1e-30f);

    for (int lev = 0; lev < 12; ++lev) {
      if (lev > 0) {
        // ---- candidate stats (skipped at level 0: tot=4096, cmin<cmax)
        int myCnt = __popc(cand);
        float cmin = FLTMAX, cmax = -FLTMAX;
#pragma unroll
        for (int j = 0; j < 16; ++j)
          if ((cand >> j) & 1) { float e = evf[j]; cmin = fminf(cmin, e); cmax = fmaxf(cmax, e); }
        int ct = myCnt;
#pragma unroll
        for (int o = 32; o; o >>= 1) {
          ct   += __shfl_xor(ct, o);
          cmin  = fminf(cmin, __shfl_xor(cmin, o));
          cmax  = fmaxf(cmax, __shfl_xor(cmax, o));
        }
        if (ln == 0) { sCnt[wv] = ct; sMin[wv] = cmin; sMax[wv] = cmax; }
        __syncthreads();
        const int tot = sCnt[0] + sCnt[1] + sCnt[2] + sCnt[3];
        cmin = fminf(fminf(sMin[0], sMin[1]), fminf(sMin[2], sMin[3]));
        cmax = fmaxf(fmaxf(sMax[0], sMax[1]), fmaxf(sMax[2], sMax[3]));

        if (tot == 0) break;

        if (cmin == cmax || lev == 11) {
          // ---- closed-form tie rule (integer masses), rank by column order
          const float v = cmax;
          const unsigned mv = mfix(v);
          int r;
          if (T <= Agt) r = 0;
          else if (mv == 0) r = tot;
          else { unsigned need = T - Agt; r = (int)((need + mv - 1) / mv); if (r > tot) r = tot; }
          int cq[4], excl[4];
#pragma unroll
          for (int q = 0; q < 4; ++q) {
            cq[q] = __popc((cand >> (4 * q)) & 0xF);
            int sc = cq[q];
#pragma unroll
            for (int o = 1; o < 64; o <<= 1) { int u = __shfl_up(sc, o); if (ln >= o) sc += u; }
            excl[q] = sc - cq[q];
            if (ln == 63) hist[wv][NBI - 4 + q] = (unsigned)(excl[q] + cq[q]);
          }
          __syncthreads();
          int qtot[4], woffq[4];
#pragma unroll
          for (int q = 0; q < 4; ++q) {
            unsigned w0 = hist[0][NBI - 4 + q], w1 = hist[1][NBI - 4 + q],
                     w2 = hist[2][NBI - 4 + q], w3 = hist[3][NBI - 4 + q];
            woffq[q] = (wv > 0 ? (int)w0 : 0) + (wv > 1 ? (int)w1 : 0) + (wv > 2 ? (int)w2 : 0);
            qtot[q]  = (int)(w0 + w1 + w2 + w3);
          }
          int qbase = 0;
#pragma unroll
          for (int q = 0; q < 4; ++q) {
            int seen = 0;
#pragma unroll
            for (int jj = 0; jj < 4; ++jj) {
              int j = 4 * q + jj;
              if ((cand >> j) & 1) {
                int rank = qbase + woffq[q] + excl[q] + seen;
                if (rank < r) keepM |= 1u << j;
                ++seen;
              }
            }
            qbase += qtot[q];
          }
          break;
        }

        if (tot <= CAPW) {
          // ---- exact tie-aware refine (float order, integer masses)
          if (t == 0) s_cnt = 0;
          __syncthreads();
#pragma unroll
          for (int j = 0; j < 16; ++j) {
            if ((cand >> j) & 1) {
              int i = atomicAdd(&s_cnt, 1);
              ge[i] = evf[j];
              gm[i] = mfix(evf[j]);
              gcol[i] = ((j >> 2) << 10) + (t << 2) + (j & 3);
            }
          }
          __syncthreads();
          const int cnt = s_cnt;
          if (t < cnt) {
            float ei = ge[t]; int ci = gcol[t];
            unsigned m = Agt;
            for (int u = 0; u < cnt; ++u) {
              float el = ge[u];
              if (el > ei || (el == ei && gcol[u] < ci)) m += gm[u];
            }
            kf[t] = (m < T) ? 1 : 0;
          }
          __syncthreads();
          for (int u = 0; u < cnt; ++u) {
            int c = gcol[u];
            if (((c >> 2) & 255) == t && kf[u])
              keepM |= 1u << (((c >> 10) << 2) | (c & 3));
          }
          break;
        }
      }

      // ---- narrowing level: integer sub-histograms (native ds_add_u32)
      const float scale = (float)NBI / width;
      {
        uint4 z; z.x = 0; z.y = 0; z.z = 0; z.w = 0;
        ((uint4*)hist[0])[t] = z; ((uint4*)hist[1])[t] = z;
        ((uint4*)hist[2])[t] = z; ((uint4*)hist[3])[t] = z;
      }
      __syncthreads();
      unsigned* Hw = hist[wv];
#pragma unroll
      for (int j = 0; j < 16; ++j) {
        if ((cand >> j) & 1) {
          float e = evf[j];
          int b = (int)((e - lo) * scale);
          b = (b < 0) ? 0 : ((b > NBI - 1) ? NBI - 1 : b);
          atomicAdd(&Hw[b], mfix(e));
        }
      }
      __syncthreads();
      unsigned hv[4];
      {
        uint4 a0 = ((const uint4*)hist[0])[t];
        uint4 a1 = ((const uint4*)hist[1])[t];
        uint4 a2 = ((const uint4*)hist[2])[t];
        uint4 a3 = ((const uint4*)hist[3])[t];
        hv[0] = a0.x + a1.x + a2.x + a3.x;
        hv[1] = a0.y + a1.y + a2.y + a3.y;
        hv[2] = a0.z + a1.z + a2.z + a3.z;
        hv[3] = a0.w + a1.w + a2.w + a3.w;
      }
      unsigned sl = (hv[0] + hv[1]) + (hv[2] + hv[3]);
      unsigned pv = sl;
#pragma unroll
      for (int o = 1; o < 64; o <<= 1) { unsigned u = __shfl_up(pv, o); if (ln >= o) pv += u; }
      if (ln == 63) sScan[wv] = pv;
      __syncthreads();
      const unsigned woff = (wv > 0 ? sScan[0] : 0u) + (wv > 1 ? sScan[1] : 0u) + (wv > 2 ? sScan[2] : 0u);
      const unsigned CM   = sScan[0] + sScan[1] + sScan[2] + sScan[3];
      if (!haveT) {
        T = (unsigned)((9ULL * (unsigned long long)CM) / 10ULL);
        haveT = true;
      }
      const unsigned incl = pv + woff;
      unsigned Arun = Agt + (CM - incl);
      int lb = -1; unsigned Ab = 0;
#pragma unroll
      for (int j = 3; j >= 0; --j) {
        unsigned bm = hv[j];
        if (Arun < T && Arun + bm >= T) { lb = j; Ab = Arun; }
        Arun += bm;
      }
      int bl = (lb >= 0) ? ((t << 2) | lb) : -1;
      int s = bl;
#pragma unroll
      for (int o = 32; o; o >>= 1) s = max(s, __shfl_xor(s, o));
      if (ln == 0) sS[wv] = s;
      __syncthreads();
      s = max(max(sS[0], sS[1]), max(sS[2], sS[3]));
      if (s < 0) { keepM |= cand; break; }
      if (bl == s) s_Ab = Ab;
      __syncthreads();
      const unsigned Abnd = s_Ab;
      unsigned nk = 0, nc = 0;
#pragma unroll
      for (int j = 0; j < 16; ++j) {
        if ((cand >> j) & 1) {
          float e = evf[j];
          int b = (int)((e - lo) * scale);
          b = (b < 0) ? 0 : ((b > NBI - 1) ? NBI - 1 : b);
          if (b > s) nk |= 1u << j;
          else if (b == s) nc |= 1u << j;
        }
      }
      keepM |= nk;
      cand = nc;
      Agt = Abnd;
      width = fmaxf(width * (1.0f / NBI), 1e-37f);
      lo = lo + (float)s * width;
    }

    // ---- exact denominator from keep mask (float)
    float dl = 0.f;
#pragma unroll
    for (int j = 0; j < 16; ++j)
      if ((keepM >> j) & 1) dl += evf[j];
#pragma unroll
    for (int o = 32; o; o >>= 1) dl += __shfl_xor(dl, o);
    if (ln == 0) sDen[wv] = dl;
    __syncthreads();
    float den = sDen[0] + sDen[1] + sDen[2] + sDen[3];
    if (den <= 0.f) den = 1.f;
    const float invd = 1.0f / den;

#pragma unroll
    for (int q = 0; q < 4; ++q) {
      u16 rr4[4];
#pragma unroll
      for (int j = 0; j < 4; ++j) {
        int b = 4 * q + j;
        float val = ((keepM >> b) & 1) ? evf[b] * invd : 0.f;
        rr4[j] = f2bf(val);
      }
      ((ushort4*)arow)[q * 256 + t] = make_ushort4(rr4[0], rr4[1], rr4[2], rr4[3]);
    }
  }
}

// ---------------------------------------------------------------------------
__global__ void cvt_all(const float* __restrict__ X,  const float* __restrict__ W1,
                        const float* __restrict__ W3, const float* __restrict__ W2,
                        const float* __restrict__ U1, const float* __restrict__ U2,
                        const float* __restrict__ U3,
                        u16* __restrict__ Xbf, u16* __restrict__ Xa0,
                        u16* __restrict__ W13b, u16* __restrict__ W2b,
                        u16* __restrict__ U1b, u16* __restrict__ U2b, u16* __restrict__ U3b)
{
  const int NX = 524288, NW = 8192, NW2 = 1024, NU = 131072;
  const int TOT = NX + 2 * NW + NW2 + 3 * NU;
  const int stride = gridDim.x * 256;
  for (int i = blockIdx.x * 256 + threadIdx.x; i < TOT; i += stride) {
    const float* s; u16* d; int rel; bool dual = false;
    if (i < NX)                       { s = X;  d = Xbf;  rel = i; dual = true; }
    else if (i < NX + NW)             { s = W1; d = W13b; rel = i - NX; }
    else if (i < NX + 2*NW)           { s = W3; d = W13b + (size_t)4*NW; rel = i - NX - NW; }
    else if (i < NX + 2*NW + NW2)     { s = W2; d = W2b;  rel = i - NX - 2*NW; }
    else if (i < NX + 2*NW + NW2 + NU){ s = U1; d = U1b;  rel = i - NX - 2*NW - NW2; }
    else if (i < NX + 2*NW + NW2+2*NU){ s = U2; d = U2b;  rel = i - NX - 2*NW - NW2 - NU; }
    else                              { s = U3; d = U3b;  rel = i - NX - 2*NW - NW2 - 2*NU; }
    float4 v = ((const float4*)s)[rel];
    ushort4 o;
    o.x = f2bf(v.x); o.y = f2bf(v.y); o.z = f2bf(v.z); o.w = f2bf(v.w);
    ((ushort4*)d)[rel] = o;
    if (dual) ((ushort4*)Xa0)[rel] = o;
  }
}

__global__ __launch_bounds__(256)
void tpose_bf(const float* __restrict__ X, u16* __restrict__ XT)
{
  __shared__ u16 tile[32][33];
  const int bc = blockIdx.x * 32;
  const int br = blockIdx.y * 32;
  const int tx = threadIdx.x & 31, ty = threadIdx.x >> 5;
#pragma unroll
  for (int i = 0; i < 32; i += 8)
    tile[ty + i][tx] = f2bf(X[(size_t)(br + ty + i) * D_IN + bc + tx]);
  __syncthreads();
#pragma unroll
  for (int i = 0; i < 32; i += 8)
    XT[(size_t)(bc + ty + i) * N_TOK + br + tx] = tile[tx][ty + i];
}

// y = X + Z0 (+ Z1); LayerNorm -> OUT.  Z1 may be null.
__global__ __launch_bounds__(256)
void ln_kernel(const float* __restrict__ X, const float* __restrict__ Z0,
               const float* __restrict__ Z1, float* __restrict__ OUT,
               const float* __restrict__ gamma, const float* __restrict__ beta)
{
  const int tid = threadIdx.x;
  __shared__ float red[4];
  __shared__ float s_mu, s_var;
  for (int rr = 0; rr < 2; ++rr) {
    const int row = blockIdx.x + rr * (N_TOK / 2);
    const size_t base = (size_t)row * D_IN;
    __syncthreads();
    float y0 = X[base + tid] + Z0[base + tid];
    float y1 = X[base + tid + 256] + Z0[base + tid + 256];
    if (Z1) { y0 += Z1[base + tid]; y1 += Z1[base + tid + 256]; }
    float s = y0 + y1;
    for (int o = 32; o; o >>= 1) s += __shfl_xor(s, o);
    if ((tid & 63) == 0) red[tid >> 6] = s;
    __syncthreads();
    if (tid == 0) s_mu = (red[0] + red[1] + red[2] + red[3]) * (1.f / D_IN);
    __syncthreads();
    const float mu = s_mu;
    float d0 = y0 - mu, d1 = y1 - mu;
    float v = d0 * d0 + d1 * d1;
    for (int o = 32; o; o >>= 1) v += __shfl_xor(v, o);
    if ((tid & 63) == 0) red[tid >> 6] = v;
    __syncthreads();
    if (tid == 0) s_var = (red[0] + red[1] + red[2] + red[3]) * (1.f / D_IN);
    __syncthreads();
    const float rs = rsqrtf(s_var + LN_EPS);
    OUT[base + tid]       = d0 * rs * gamma[tid]       + beta[tid];
    OUT[base + tid + 256] = d1 * rs * gamma[tid + 256] + beta[tid + 256];
  }
}

// ---------------------------------------------------------------------------
extern "C" void kernel_launch(void* const* d_in, const int* in_sizes, int n_in,
                              void* d_out, int out_size, void* d_ws, size_t ws_size,
                              hipStream_t stream)
{
  const float* X     = (const float*)d_in[0];
  const float* W1    = (const float*)d_in[1];
  const float* W2    = (const float*)d_in[2];
  const float* W3    = (const float*)d_in[3];
  const float* U1    = (const float*)d_in[4];
  const float* U2    = (const float*)d_in[5];
  const float* U3    = (const float*)d_in[6];
  const float* gamma = (const float*)d_in[7];
  const float* beta  = (const float*)d_in[8];

#define NILSEG nullptr, 0, 0, nullptr, 0

  char* w = (char*)d_ws;
  u16* S16    = (u16*)w;              w += (size_t)N_TOK * N_TOK * 2;   // 32 MB
  u16* Xbf    = (u16*)w;              w += (size_t)N_TOK * D_IN * 2;
  u16* Xa0    = (u16*)w;              w += (size_t)N_TOK * D_IN * 2;
  u16* Xa1    = (u16*)w;              w += (size_t)N_TOK * D_IN * 2;
  u16* XaT0   = (u16*)w;              w += (size_t)D_IN * N_TOK * 2;
  u16* XaT1   = (u16*)w;              w += (size_t)D_IN * N_TOK * 2;
  u16* hb     = (u16*)w;              w += (size_t)N_TOK * D_ATTN * 2;
  u16* qb     = (u16*)w;              w += (size_t)N_TOK * D_ATTN * 2;
  u16* kb     = (u16*)w;              w += (size_t)N_TOK * D_ATTN * 2;
  u16* W13b   = (u16*)w;              w += (size_t)2 * D_ATTN * D_IN * 2;
  u16* W2b    = (u16*)w;              w += (size_t)D_ATTN * D_ATTN * 2;
  u16* U1b    = (u16*)w;              w += (size_t)2 * D_IN * D_IN * 2;
  u16* U2b    = (u16*)w;              w += (size_t)2 * D_IN * D_IN * 2;
  u16* U3b    = (u16*)w;              w += (size_t)2 * D_IN * D_IN * 2;

  size_t used = (size_t)(w - (char*)d_ws);
  u16* Abuf;
  int  apitch = N_TOK;
  if (ws_size >= used + (size_t)N_TOK * N_TOK * 2) {
    Abuf = (u16*)w;
    w += (size_t)N_TOK * N_TOK * 2;
  } else {
    Abuf = S16;                        // in-place fallback (bounded algo; safe)
  }
  used = (size_t)(w - (char*)d_ws);
  float* Zp = nullptr;
  const bool splitK = (ws_size >= used + 4 * (size_t)N_TOK * D_IN * 4);
  if (splitK) { Zp = (float*)w; w += 4 * (size_t)N_TOK * D_IN * 4; }
  used = (size_t)(w - (char*)d_ws);
  float* Zq = nullptr;                 // proj split-K partials (2x 8MB)
  const bool projSplit = (ws_size >= used + 2 * (size_t)N_TOK * D_IN * 4);
  if (projSplit) { Zq = (float*)w; w += 2 * (size_t)N_TOK * D_IN * 4; }

  float* Z = (float*)d_out;

  if (projSplit) {
    hipMemsetAsync(Zq, 0, 2 * (size_t)N_TOK * D_IN * 4, stream);
  } else {
    hipMemsetAsync(d_out, 0, (size_t)N_TOK * D_IN * 4, stream);
  }

  cvt_all<<<1024, 256, 0, stream>>>(X, W1, W3, W2, U1, U2, U3,
                                    Xbf, Xa0, W13b, W2b, U1b, U2b, U3b);
  tpose_bf<<<dim3(D_IN / 32, N_TOK / 32), 256, 0, stream>>>(X, XaT0);

  const size_t UST = (size_t)D_IN * D_IN;   // per-step U stride

  // Upfront: Z += Xf1@U1[0] + Xb1@U2[0] + Xf2@U1[1] + Xb2@U2[1]
  // (depends only on X; 4-segment, split-K x2, DB=2)
  if (projSplit) {
    gemm128<3, 4, D_IN / 2, 2><<<dim3(8, 32, 2), 256, 0, stream>>>(
        Xbf, D_IN, -1, U1b, D_IN,
        Xbf, D_IN, +1, U2b, D_IN,
        Xbf, D_IN, -2, U1b + UST, D_IN,
        Xbf, D_IN, +2, U2b + UST, D_IN,
        Zq, nullptr, nullptr, D_IN, N_TOK * D_IN);
  }

  u16* XaC[2]  = {Xa0, Xa1};
  u16* XaTC[2] = {XaT0, XaT1};

  for (int n = 0; n < 2; ++n) {
    const int cur = n & 1, nxt = cur ^ 1;
    const size_t uoff = (size_t)n * UST;
    // h = tanh(Xa @ W1^T), k = Xa @ W3^T  (fused; TOTAL=8, DB=3)
    gemm128<5, 1, D_IN><<<dim3(2, 32), 256, 0, stream>>>(
        XaC[cur], D_IN, 0, W13b, D_IN,
        NILSEG, NILSEG, NILSEG,
        nullptr, hb, kb, 64, 64);
    // q = h @ W2^T  (TOTAL=1)
    gemm128<2, 1, D_ATTN><<<dim3(1, 32), 256, 0, stream>>>(
        hb, D_ATTN, 0, W2b, D_ATTN,
        NILSEG, NILSEG, NILSEG,
        nullptr, qb, nullptr, D_ATTN, 0);
    // S = q @ k^T -> bf16  (2048 blocks)
    gemm128<2, 1, D_ATTN><<<dim3(64, 32), 256, 0, stream>>>(
        qb, D_ATTN, 0, kb, D_ATTN,
        NILSEG, NILSEG, NILSEG,
        nullptr, S16, nullptr, N_TOK, 0);
    // softmax + top-p -> A
    nucleus_block<<<N_TOK / 2, 256, 0, stream>>>(S16, Abuf, apitch);
    // Xa_new = A @ Xa
    if (splitK) {
      gemm128<6, 1, N_TOK / 4, 2><<<dim3(8, 32, 4), 256, 0, stream>>>(
          Abuf, apitch, 0, XaTC[cur], N_TOK,
          NILSEG, NILSEG, NILSEG,
          Zp, nullptr, nullptr, D_IN, N_TOK * D_IN);
      if (n == 0)
        pvfix<true><<<dim3(D_IN / 64, N_TOK / 64), 256, 0, stream>>>(
            Zp, XaC[nxt], XaTC[nxt]);
      else
        pvfix<false><<<dim3(D_IN / 64, N_TOK / 64), 256, 0, stream>>>(
            Zp, XaC[nxt], nullptr);
    } else {
      gemm128<4, 1, N_TOK><<<dim3(8, 32), 256, 0, stream>>>(
          Abuf, apitch, 0, XaTC[cur], N_TOK,
          NILSEG, NILSEG, NILSEG,
          nullptr, XaC[nxt], XaTC[nxt], D_IN, N_TOK);
    }
    // Z += Xa_new @ U3[n]^T   (U3-only; U1/U2 hoisted upfront)
    if (projSplit) {
      gemm128<3, 1, D_IN / 2, 2><<<dim3(8, 32, 2), 256, 0, stream>>>(
          XaC[nxt], D_IN, 0, U3b + uoff, D_IN,
          NILSEG, NILSEG, NILSEG,
          Zq, nullptr, nullptr, D_IN, N_TOK * D_IN);
    } else {
      gemm128<3, 3, D_IN><<<dim3(8, 32), 256, 0, stream>>>(
          Xbf, D_IN, -(n + 1), U1b + uoff, D_IN,
          Xbf, D_IN,  (n + 1), U2b + uoff, D_IN,
          XaC[nxt], D_IN, 0,   U3b + uoff, D_IN,
          NILSEG,
          Z, nullptr, nullptr, D_IN, 0);
    }
  }

  // y = X + Z(0)+Z(1) ; LayerNorm -> d_out
  if (projSplit) {
    ln_kernel<<<N_TOK / 2, 256, 0, stream>>>(
        X, Zq, Zq + (size_t)N_TOK * D_IN, (float*)d_out, gamma, beta);
  } else {
    ln_kernel<<<N_TOK / 2, 256, 0, stream>>>(
        X, Z, nullptr, (float*)d_out, gamma, beta);
  }
}

// Round 17
// 337.111 us; speedup vs baseline: 1.0689x; 1.0689x over previous
//
#include <hip/hip_runtime.h>
#include <hip/hip_bf16.h>
#include <math.h>

typedef short bf16x8 __attribute__((ext_vector_type(8)));
typedef float f32x4 __attribute__((ext_vector_type(4)));
typedef unsigned short u16;
typedef unsigned long long u64;

#define N_TOK  4096
#define D_IN   512
#define D_ATTN 64
#define NBI    1024
#define CAPW   128
#define TOPP   0.9f
#define LN_EPS 1e-5f
#define AMAXV  (N_TOK - 1)
#define FLTMAX 3.402823466e38f
#define MSCALE 524288.0f   /* 2^19 fixed-point mass scale */

__device__ __forceinline__ u16 f2bf(float f) {
  unsigned int u = __float_as_uint(f);
  return (u16)((u + 0x7FFFu + ((u >> 16) & 1u)) >> 16);
}

__device__ __forceinline__ float bf2f(u16 v) {
  return __uint_as_float(((unsigned)v) << 16);
}

__device__ __forceinline__ unsigned mfix(float e) {
  return (unsigned)(e * MSCALE + 0.5f);
}

__device__ __forceinline__ void gload16(const u16* g, u16* l) {
  __builtin_amdgcn_global_load_lds(
      (const __attribute__((address_space(1))) unsigned int*)g,
      (__attribute__((address_space(3))) unsigned int*)l, 16, 0, 0);
}

// ---------------------------------------------------------------------------
// gemm128 (R13/R14 proven config): C = sum_seg rowmap(A_s) @ B_s^T.
// BM=128, BN=64, BK=64. DB = min(TOTAL,3) LDS buffers; counted-vmcnt
// pipeline for long-K; 24 KB LDS for TOTAL=1.
// EPI: 0 f32; 1 tanh->bf16; 2 bf16; 3 f32 += (z-partial); 4 bf16 dual;
//      5 split col<64 tanh->Cb / col>=64 CbT; 6 f32 -> Cf + z*ldct
// ---------------------------------------------------------------------------
template<int EPI, int NSEG, int KSEG>
__global__ __launch_bounds__(256)
void gemm128(const u16* __restrict__ A0, int lda0, int sh0, const u16* __restrict__ B0, int ldb0,
             const u16* __restrict__ A1, int lda1, int sh1, const u16* __restrict__ B1, int ldb1,
             const u16* __restrict__ A2, int lda2, int sh2, const u16* __restrict__ B2, int ldb2,
             float* __restrict__ Cf, u16* __restrict__ Cb, u16* __restrict__ CbT,
             int ldc, int ldct)
{
  constexpr int BN = 64;
  constexpr int NF = BN / 32;
  constexpr int IPSEG = KSEG >> 6;
  constexpr int TOTAL = NSEG * IPSEG;
  constexpr int DB = (TOTAL < 3) ? TOTAL : 3;

  __shared__ u16 sA[DB][128 * 64];
  __shared__ u16 sB[DB][BN * 64];

  const int tid  = threadIdx.x;
  const int wave = tid >> 6;
  const int lane = tid & 63;
  const int l15  = lane & 15;
  const int l4   = lane >> 4;
  const int brow = blockIdx.y << 7;
  const int bcol = blockIdx.x * BN;
  const int kz   = blockIdx.z * KSEG;
  const int wr64 = (wave >> 1) << 6;
  const int wcol = (wave & 1) * (BN >> 1);

  auto stage = [&](int buf, int it) {
    int seg = (NSEG == 1) ? 0 : (it / IPSEG);
    int kk  = (NSEG == 1) ? (it << 6) : ((it % IPSEG) << 6);
    const u16 *Ab, *Bb; int la, lb, sh;
    if (seg == 0)      { Ab = A0; la = lda0; sh = sh0; Bb = B0; lb = ldb0; }
    else if (seg == 1) { Ab = A1; la = lda1; sh = sh1; Bb = B1; lb = ldb1; }
    else               { Ab = A2; la = lda2; sh = sh2; Bb = B2; lb = ldb2; }
    kk += kz;
#pragma unroll
    for (int q = 0; q < 4; ++q) {              // A tile 128x64
      int idx = q * 256 + tid;
      int row = idx >> 3;
      int chunk = (idx & 7) ^ (row & 7);
      int r = brow + row + sh;
      r = (r < 0) ? 0 : ((r > AMAXV) ? AMAXV : r);
      gload16(Ab + (size_t)r * la + kk + chunk * 8, &sA[buf][idx * 8]);
    }
#pragma unroll
    for (int q = 0; q < BN / 32; ++q) {        // B tile 64x64
      int idx = q * 256 + tid;
      int row = idx >> 3;
      int chunk = (idx & 7) ^ (row & 7);
      gload16(Bb + (size_t)(bcol + row) * lb + kk + chunk * 8, &sB[buf][idx * 8]);
    }
  };

  f32x4 acc[4][NF];
#pragma unroll
  for (int m = 0; m < 4; ++m)
#pragma unroll
    for (int n = 0; n < NF; ++n) {
      acc[m][n][0] = 0.f; acc[m][n][1] = 0.f; acc[m][n][2] = 0.f; acc[m][n][3] = 0.f;
    }

  stage(0, 0);
  if (TOTAL > 1) stage(1 % DB, 1);

  for (int i = 0; i < TOTAL; ++i) {
    if (i + 1 < TOTAL) asm volatile("s_waitcnt vmcnt(6)" ::: "memory");
    else               asm volatile("s_waitcnt vmcnt(0)" ::: "memory");
    __builtin_amdgcn_s_barrier();
    if (i + 2 < TOTAL) stage((i + 2) % DB, i + 2);
    const int c = i % DB;
#pragma unroll
    for (int ks = 0; ks < 2; ++ks) {
      bf16x8 af[4], bfr[NF];
#pragma unroll
      for (int m = 0; m < 4; ++m) {
        int ar = wr64 + m * 16 + l15;
        af[m] = *(const bf16x8*)&sA[c][ar * 64 + (((ks << 2) + l4) ^ (ar & 7)) * 8];
      }
#pragma unroll
      for (int n = 0; n < NF; ++n) {
        int br = wcol + n * 16 + l15;
        bfr[n] = *(const bf16x8*)&sB[c][br * 64 + (((ks << 2) + l4) ^ (br & 7)) * 8];
      }
#pragma unroll
      for (int m = 0; m < 4; ++m)
#pragma unroll
        for (int n = 0; n < NF; ++n)
          acc[m][n] = __builtin_amdgcn_mfma_f32_16x16x32_bf16(af[m], bfr[n], acc[m][n], 0, 0, 0);
    }
  }

  float* Cfz = (EPI == 6 || EPI == 3) ? (Cf + (size_t)blockIdx.z * (size_t)ldct) : Cf;
#pragma unroll
  for (int m = 0; m < 4; ++m)
#pragma unroll
    for (int n = 0; n < NF; ++n)
#pragma unroll
      for (int r = 0; r < 4; ++r) {
        const int row = brow + wr64 + m * 16 + l4 * 4 + r;
        const int col = bcol + wcol + n * 16 + l15;
        const float v = acc[m][n][r];
        if (EPI == 0) Cf[(size_t)row * ldc + col] = v;
        if (EPI == 1) Cb[(size_t)row * ldc + col] = f2bf(tanhf(v));
        if (EPI == 2) Cb[(size_t)row * ldc + col] = f2bf(v);
        if (EPI == 3) Cfz[(size_t)row * ldc + col] += v;
        if (EPI == 4) {
          u16 hv = f2bf(v);
          Cb [(size_t)row * ldc  + col] = hv;
          CbT[(size_t)col * ldct + row] = hv;
        }
        if (EPI == 5) {
          if (col < 64) Cb [(size_t)row * 64 + col]        = f2bf(tanhf(v));
          else          CbT[(size_t)row * 64 + (col - 64)] = f2bf(v);
        }
        if (EPI == 6) Cfz[(size_t)row * ldc + col] = v;
      }
}

// ---------------------------------------------------------------------------
// pvfix: Xa = bf16(sum of 4 split-K partials); XaT = Xa^T only if WRT
// (last step's XaT is dead — skip the transpose pass and 4 MB store).
// ---------------------------------------------------------------------------
template<bool WRT>
__global__ __launch_bounds__(256)
void pvfix(const float* __restrict__ Zp, u16* __restrict__ Xa, u16* __restrict__ XaT)
{
  const size_t st = (size_t)N_TOK * D_IN;
  __shared__ u16 tile[64][65];
  const int bx = blockIdx.x, by = blockIdx.y;
  const int t = threadIdx.x;
  const int tx = t & 15, ty = t >> 4;
#pragma unroll
  for (int i = 0; i < 4; ++i) {
    int r = by * 64 + ty + 16 * i;
    int c = bx * 64 + tx * 4;
    size_t idx = (size_t)r * D_IN + c;
    float4 a = *(const float4*)&Zp[idx];
    float4 b = *(const float4*)&Zp[idx + st];
    float4 d = *(const float4*)&Zp[idx + 2 * st];
    float4 e = *(const float4*)&Zp[idx + 3 * st];
    u16 q0 = f2bf(a.x + b.x + d.x + e.x), q1 = f2bf(a.y + b.y + d.y + e.y);
    u16 q2 = f2bf(a.z + b.z + d.z + e.z), q3 = f2bf(a.w + b.w + d.w + e.w);
    *(ushort4*)&Xa[idx] = make_ushort4(q0, q1, q2, q3);
    if (WRT) {
      tile[ty + 16 * i][tx * 4 + 0] = q0;
      tile[ty + 16 * i][tx * 4 + 1] = q1;
      tile[ty + 16 * i][tx * 4 + 2] = q2;
      tile[ty + 16 * i][tx * 4 + 3] = q3;
    }
  }
  if (WRT) {
    __syncthreads();
#pragma unroll
    for (int i = 0; i < 4; ++i) {
      int cc = ty + 16 * i;
      int rq = tx * 4;
      u16 o0 = tile[rq + 0][cc], o1 = tile[rq + 1][cc];
      u16 o2 = tile[rq + 2][cc], o3 = tile[rq + 3][cc];
      *(ushort4*)&XaT[(size_t)(bx * 64 + cc) * N_TOK + by * 64 + rq] =
          make_ushort4(o0, o1, o2, o3);
    }
  }
}

// ---------------------------------------------------------------------------
// Block-per-row nucleus (R14 proven version: R9 structure, bf16 input,
// stats reduce every level — keeps VGPR at 64 = 8 waves/SIMD).
// ---------------------------------------------------------------------------
__global__ __launch_bounds__(256)
void nucleus_block(const u16* __restrict__ S, u16* __restrict__ A, int apitch)
{
  const int t = threadIdx.x;
  const int wv = t >> 6, ln = t & 63;

  __shared__ unsigned hist[4][NBI];        // 16 KB
  __shared__ float ge[CAPW];
  __shared__ int   gcol[CAPW];
  __shared__ unsigned gm[CAPW];
  __shared__ unsigned char kf[CAPW];
  __shared__ float sMin[4], sMax[4], sDen[4];
  __shared__ int   sCnt[4], sS[4];
  __shared__ unsigned sScan[4];
  __shared__ unsigned s_Ab;
  __shared__ int   s_cnt;

  for (int rr = 0; rr < 2; ++rr) {
    const int row = blockIdx.x + rr * (N_TOK / 2);
    const u16* srow = S + (size_t)row * N_TOK;
    u16* arow = A + (size_t)row * apitch;

    __syncthreads();

    float evf[16];
    float lmax = -FLTMAX, lmin = FLTMAX;
#pragma unroll
    for (int q = 0; q < 4; ++q) {
      ushort4 v = ((const ushort4*)srow)[q * 256 + t];
      float e0 = bf2f(v.x), e1 = bf2f(v.y), e2 = bf2f(v.z), e3 = bf2f(v.w);
      evf[4*q+0] = e0; evf[4*q+1] = e1; evf[4*q+2] = e2; evf[4*q+3] = e3;
      lmax = fmaxf(lmax, fmaxf(fmaxf(e0, e1), fmaxf(e2, e3)));
      lmin = fminf(lmin, fminf(fminf(e0, e1), fminf(e2, e3)));
    }
#pragma unroll
    for (int o = 32; o; o >>= 1) {
      lmax = fmaxf(lmax, __shfl_xor(lmax, o));
      lmin = fminf(lmin, __shfl_xor(lmin, o));
    }
    if (ln == 0) { sMax[wv] = lmax; sMin[wv] = lmin; }
    __syncthreads();
    const float smax = fmaxf(fmaxf(sMax[0], sMax[1]), fmaxf(sMax[2], sMax[3]));
    const float smin = fminf(fminf(sMin[0], sMin[1]), fminf(sMin[2], sMin[3]));

#pragma unroll
    for (int j = 0; j < 16; ++j) evf[j] = __expf(evf[j] - smax);

    unsigned keepM = 0, cand = 0xFFFFu;
    unsigned Agt = 0, T = 0;
    bool haveT = false;
    float lo = __expf(smin - smax);
    float width = fmaxf(1.0f - lo, 1e-30f);

    for (int lev = 0; lev < 12; ++lev) {
      __syncthreads();
      {
        uint4 z; z.x = 0; z.y = 0; z.z = 0; z.w = 0;
        ((uint4*)hist[0])[t] = z; ((uint4*)hist[1])[t] = z;
        ((uint4*)hist[2])[t] = z; ((uint4*)hist[3])[t] = z;
      }
      int myCnt = __popc(cand);
      float cmin = FLTMAX, cmax = -FLTMAX;
#pragma unroll
      for (int j = 0; j < 16; ++j)
        if ((cand >> j) & 1) { float e = evf[j]; cmin = fminf(cmin, e); cmax = fmaxf(cmax, e); }
      int ct = myCnt;
#pragma unroll
      for (int o = 32; o; o >>= 1) {
        ct   += __shfl_xor(ct, o);
        cmin  = fminf(cmin, __shfl_xor(cmin, o));
        cmax  = fmaxf(cmax, __shfl_xor(cmax, o));
      }
      if (ln == 0) { sCnt[wv] = ct; sMin[wv] = cmin; sMax[wv] = cmax; }
      __syncthreads();
      const int tot = sCnt[0] + sCnt[1] + sCnt[2] + sCnt[3];
      cmin = fminf(fminf(sMin[0], sMin[1]), fminf(sMin[2], sMin[3]));
      cmax = fmaxf(fmaxf(sMax[0], sMax[1]), fmaxf(sMax[2], sMax[3]));

      if (tot == 0) break;

      if (haveT && (cmin == cmax || lev == 11)) {
        const float v = cmax;
        const unsigned mv = mfix(v);
        int r;
        if (T <= Agt) r = 0;
        else if (mv == 0) r = tot;
        else { unsigned need = T - Agt; r = (int)((need + mv - 1) / mv); if (r > tot) r = tot; }
        int cq[4], excl[4];
#pragma unroll
        for (int q = 0; q < 4; ++q) {
          cq[q] = __popc((cand >> (4 * q)) & 0xF);
          int sc = cq[q];
#pragma unroll
          for (int o = 1; o < 64; o <<= 1) { int u = __shfl_up(sc, o); if (ln >= o) sc += u; }
          excl[q] = sc - cq[q];
          if (ln == 63) hist[wv][NBI - 4 + q] = (unsigned)(excl[q] + cq[q]);
        }
        __syncthreads();
        int qtot[4], woffq[4];
#pragma unroll
        for (int q = 0; q < 4; ++q) {
          unsigned w0 = hist[0][NBI - 4 + q], w1 = hist[1][NBI - 4 + q],
                   w2 = hist[2][NBI - 4 + q], w3 = hist[3][NBI - 4 + q];
          woffq[q] = (wv > 0 ? (int)w0 : 0) + (wv > 1 ? (int)w1 : 0) + (wv > 2 ? (int)w2 : 0);
          qtot[q]  = (int)(w0 + w1 + w2 + w3);
        }
        int qbase = 0;
#pragma unroll
        for (int q = 0; q < 4; ++q) {
          int seen = 0;
#pragma unroll
          for (int jj = 0; jj < 4; ++jj) {
            int j = 4 * q + jj;
            if ((cand >> j) & 1) {
              int rank = qbase + woffq[q] + excl[q] + seen;
              if (rank < r) keepM |= 1u << j;
              ++seen;
            }
          }
          qbase += qtot[q];
        }
        break;
      }

      if (haveT && tot <= CAPW) {
        if (t == 0) s_cnt = 0;
        __syncthreads();
#pragma unroll
        for (int j = 0; j < 16; ++j) {
          if ((cand >> j) & 1) {
            int i = atomicAdd(&s_cnt, 1);
            ge[i] = evf[j];
            gm[i] = mfix(evf[j]);
            gcol[i] = ((j >> 2) << 10) + (t << 2) + (j & 3);
          }
        }
        __syncthreads();
        const int cnt = s_cnt;
        if (t < cnt) {
          float ei = ge[t]; int ci = gcol[t];
          unsigned m = Agt;
          for (int u = 0; u < cnt; ++u) {
            float el = ge[u];
            if (el > ei || (el == ei && gcol[u] < ci)) m += gm[u];
          }
          kf[t] = (m < T) ? 1 : 0;
        }
        __syncthreads();
        for (int u = 0; u < cnt; ++u) {
          int c = gcol[u];
          if (((c >> 2) & 255) == t && kf[u])
            keepM |= 1u << (((c >> 10) << 2) | (c & 3));
        }
        break;
      }

      const float scale = (float)NBI / width;
      __syncthreads();
      unsigned* Hw = hist[wv];
#pragma unroll
      for (int j = 0; j < 16; ++j) {
        if ((cand >> j) & 1) {
          float e = evf[j];
          int b = (int)((e - lo) * scale);
          b = (b < 0) ? 0 : ((b > NBI - 1) ? NBI - 1 : b);
          atomicAdd(&Hw[b], mfix(e));
        }
      }
      __syncthreads();
      unsigned hv[4];
      {
        uint4 a0 = ((const uint4*)hist[0])[t];
        uint4 a1 = ((const uint4*)hist[1])[t];
        uint4 a2 = ((const uint4*)hist[2])[t];
        uint4 a3 = ((const uint4*)hist[3])[t];
        hv[0] = a0.x + a1.x + a2.x + a3.x;
        hv[1] = a0.y + a1.y + a2.y + a3.y;
        hv[2] = a0.z + a1.z + a2.z + a3.z;
        hv[3] = a0.w + a1.w + a2.w + a3.w;
      }
      unsigned sl = (hv[0] + hv[1]) + (hv[2] + hv[3]);
      unsigned pv = sl;
#pragma unroll
      for (int o = 1; o < 64; o <<= 1) { unsigned u = __shfl_up(pv, o); if (ln >= o) pv += u; }
      if (ln == 63) sScan[wv] = pv;
      __syncthreads();
      const unsigned woff = (wv > 0 ? sScan[0] : 0u) + (wv > 1 ? sScan[1] : 0u) + (wv > 2 ? sScan[2] : 0u);
      const unsigned CM   = sScan[0] + sScan[1] + sScan[2] + sScan[3];
      if (!haveT) {
        T = (unsigned)((9ULL * (unsigned long long)CM) / 10ULL);
        haveT = true;
      }
      const unsigned incl = pv + woff;
      unsigned Arun = Agt + (CM - incl);
      int lb = -1; unsigned Ab = 0;
#pragma unroll
      for (int j = 3; j >= 0; --j) {
        unsigned bm = hv[j];
        if (Arun < T && Arun + bm >= T) { lb = j; Ab = Arun; }
        Arun += bm;
      }
      int bl = (lb >= 0) ? ((t << 2) | lb) : -1;
      int s = bl;
#pragma unroll
      for (int o = 32; o; o >>= 1) s = max(s, __shfl_xor(s, o));
      if (ln == 0) sS[wv] = s;
      __syncthreads();
      s = max(max(sS[0], sS[1]), max(sS[2], sS[3]));
      if (s < 0) { keepM |= cand; break; }
      if (bl == s) s_Ab = Ab;
      __syncthreads();
      const unsigned Abnd = s_Ab;
      unsigned nk = 0, nc = 0;
#pragma unroll
      for (int j = 0; j < 16; ++j) {
        if ((cand >> j) & 1) {
          float e = evf[j];
          int b = (int)((e - lo) * scale);
          b = (b < 0) ? 0 : ((b > NBI - 1) ? NBI - 1 : b);
          if (b > s) nk |= 1u << j;
          else if (b == s) nc |= 1u << j;
        }
      }
      keepM |= nk;
      cand = nc;
      Agt = Abnd;
      width = fmaxf(width * (1.0f / NBI), 1e-37f);
      lo = lo + (float)s * width;
    }

    // ---- exact denominator from keep mask (float)
    float dl = 0.f;
#pragma unroll
    for (int j = 0; j < 16; ++j)
      if ((keepM >> j) & 1) dl += evf[j];
#pragma unroll
    for (int o = 32; o; o >>= 1) dl += __shfl_xor(dl, o);
    if (ln == 0) sDen[wv] = dl;
    __syncthreads();
    float den = sDen[0] + sDen[1] + sDen[2] + sDen[3];
    if (den <= 0.f) den = 1.f;
    const float invd = 1.0f / den;

#pragma unroll
    for (int q = 0; q < 4; ++q) {
      u16 rr4[4];
#pragma unroll
      for (int j = 0; j < 4; ++j) {
        int b = 4 * q + j;
        float val = ((keepM >> b) & 1) ? evf[b] * invd : 0.f;
        rr4[j] = f2bf(val);
      }
      ((ushort4*)arow)[q * 256 + t] = make_ushort4(rr4[0], rr4[1], rr4[2], rr4[3]);
    }
  }
}

// ---------------------------------------------------------------------------
__global__ void cvt_all(const float* __restrict__ X,  const float* __restrict__ W1,
                        const float* __restrict__ W3, const float* __restrict__ W2,
                        const float* __restrict__ U1, const float* __restrict__ U2,
                        const float* __restrict__ U3,
                        u16* __restrict__ Xbf, u16* __restrict__ Xa0,
                        u16* __restrict__ W13b, u16* __restrict__ W2b,
                        u16* __restrict__ U1b, u16* __restrict__ U2b, u16* __restrict__ U3b)
{
  const int NX = 524288, NW = 8192, NW2 = 1024, NU = 131072;
  const int TOT = NX + 2 * NW + NW2 + 3 * NU;
  const int stride = gridDim.x * 256;
  for (int i = blockIdx.x * 256 + threadIdx.x; i < TOT; i += stride) {
    const float* s; u16* d; int rel; bool dual = false;
    if (i < NX)                       { s = X;  d = Xbf;  rel = i; dual = true; }
    else if (i < NX + NW)             { s = W1; d = W13b; rel = i - NX; }
    else if (i < NX + 2*NW)           { s = W3; d = W13b + (size_t)4*NW; rel = i - NX - NW; }
    else if (i < NX + 2*NW + NW2)     { s = W2; d = W2b;  rel = i - NX - 2*NW; }
    else if (i < NX + 2*NW + NW2 + NU){ s = U1; d = U1b;  rel = i - NX - 2*NW - NW2; }
    else if (i < NX + 2*NW + NW2+2*NU){ s = U2; d = U2b;  rel = i - NX - 2*NW - NW2 - NU; }
    else                              { s = U3; d = U3b;  rel = i - NX - 2*NW - NW2 - 2*NU; }
    float4 v = ((const float4*)s)[rel];
    ushort4 o;
    o.x = f2bf(v.x); o.y = f2bf(v.y); o.z = f2bf(v.z); o.w = f2bf(v.w);
    ((ushort4*)d)[rel] = o;
    if (dual) ((ushort4*)Xa0)[rel] = o;
  }
}

__global__ __launch_bounds__(256)
void tpose_bf(const float* __restrict__ X, u16* __restrict__ XT)
{
  __shared__ u16 tile[32][33];
  const int bc = blockIdx.x * 32;
  const int br = blockIdx.y * 32;
  const int tx = threadIdx.x & 31, ty = threadIdx.x >> 5;
#pragma unroll
  for (int i = 0; i < 32; i += 8)
    tile[ty + i][tx] = f2bf(X[(size_t)(br + ty + i) * D_IN + bc + tx]);
  __syncthreads();
#pragma unroll
  for (int i = 0; i < 32; i += 8)
    XT[(size_t)(bc + ty + i) * N_TOK + br + tx] = tile[tx][ty + i];
}

// y = X + Z0 (+ Z1); LayerNorm -> OUT.  Z1 may be null.
__global__ __launch_bounds__(256)
void ln_kernel(const float* __restrict__ X, const float* __restrict__ Z0,
               const float* __restrict__ Z1, float* __restrict__ OUT,
               const float* __restrict__ gamma, const float* __restrict__ beta)
{
  const int tid = threadIdx.x;
  __shared__ float red[4];
  __shared__ float s_mu, s_var;
  for (int rr = 0; rr < 2; ++rr) {
    const int row = blockIdx.x + rr * (N_TOK / 2);
    const size_t base = (size_t)row * D_IN;
    __syncthreads();
    float y0 = X[base + tid] + Z0[base + tid];
    float y1 = X[base + tid + 256] + Z0[base + tid + 256];
    if (Z1) { y0 += Z1[base + tid]; y1 += Z1[base + tid + 256]; }
    float s = y0 + y1;
    for (int o = 32; o; o >>= 1) s += __shfl_xor(s, o);
    if ((tid & 63) == 0) red[tid >> 6] = s;
    __syncthreads();
    if (tid == 0) s_mu = (red[0] + red[1] + red[2] + red[3]) * (1.f / D_IN);
    __syncthreads();
    const float mu = s_mu;
    float d0 = y0 - mu, d1 = y1 - mu;
    float v = d0 * d0 + d1 * d1;
    for (int o = 32; o; o >>= 1) v += __shfl_xor(v, o);
    if ((tid & 63) == 0) red[tid >> 6] = v;
    __syncthreads();
    if (tid == 0) s_var = (red[0] + red[1] + red[2] + red[3]) * (1.f / D_IN);
    __syncthreads();
    const float rs = rsqrtf(s_var + LN_EPS);
    OUT[base + tid]       = d0 * rs * gamma[tid]       + beta[tid];
    OUT[base + tid + 256] = d1 * rs * gamma[tid + 256] + beta[tid + 256];
  }
}

// ---------------------------------------------------------------------------
extern "C" void kernel_launch(void* const* d_in, const int* in_sizes, int n_in,
                              void* d_out, int out_size, void* d_ws, size_t ws_size,
                              hipStream_t stream)
{
  const float* X     = (const float*)d_in[0];
  const float* W1    = (const float*)d_in[1];
  const float* W2    = (const float*)d_in[2];
  const float* W3    = (const float*)d_in[3];
  const float* U1    = (const float*)d_in[4];
  const float* U2    = (const float*)d_in[5];
  const float* U3    = (const float*)d_in[6];
  const float* gamma = (const float*)d_in[7];
  const float* beta  = (const float*)d_in[8];

  char* w = (char*)d_ws;
  u16* S16    = (u16*)w;              w += (size_t)N_TOK * N_TOK * 2;   // 32 MB
  u16* Xbf    = (u16*)w;              w += (size_t)N_TOK * D_IN * 2;
  u16* Xa0    = (u16*)w;              w += (size_t)N_TOK * D_IN * 2;
  u16* Xa1    = (u16*)w;              w += (size_t)N_TOK * D_IN * 2;
  u16* XaT0   = (u16*)w;              w += (size_t)D_IN * N_TOK * 2;
  u16* XaT1   = (u16*)w;              w += (size_t)D_IN * N_TOK * 2;
  u16* hb     = (u16*)w;              w += (size_t)N_TOK * D_ATTN * 2;
  u16* qb     = (u16*)w;              w += (size_t)N_TOK * D_ATTN * 2;
  u16* kb     = (u16*)w;              w += (size_t)N_TOK * D_ATTN * 2;
  u16* W13b   = (u16*)w;              w += (size_t)2 * D_ATTN * D_IN * 2;
  u16* W2b    = (u16*)w;              w += (size_t)D_ATTN * D_ATTN * 2;
  u16* U1b    = (u16*)w;              w += (size_t)2 * D_IN * D_IN * 2;
  u16* U2b    = (u16*)w;              w += (size_t)2 * D_IN * D_IN * 2;
  u16* U3b    = (u16*)w;              w += (size_t)2 * D_IN * D_IN * 2;

  size_t used = (size_t)(w - (char*)d_ws);
  u16* Abuf;
  int  apitch = N_TOK;
  if (ws_size >= used + (size_t)N_TOK * N_TOK * 2) {
    Abuf = (u16*)w;
    w += (size_t)N_TOK * N_TOK * 2;
  } else {
    Abuf = S16;                        // in-place fallback (bounded algo; safe)
  }
  used = (size_t)(w - (char*)d_ws);
  float* Zp = nullptr;
  const bool splitK = (ws_size >= used + 4 * (size_t)N_TOK * D_IN * 4);
  if (splitK) { Zp = (float*)w; w += 4 * (size_t)N_TOK * D_IN * 4; }
  used = (size_t)(w - (char*)d_ws);
  float* Zq = nullptr;                 // proj split-K partials (2x 8MB)
  const bool projSplit = (ws_size >= used + 2 * (size_t)N_TOK * D_IN * 4);
  if (projSplit) { Zq = (float*)w; w += 2 * (size_t)N_TOK * D_IN * 4; }

  float* Z = (float*)d_out;

  if (projSplit) {
    hipMemsetAsync(Zq, 0, 2 * (size_t)N_TOK * D_IN * 4, stream);
  } else {
    hipMemsetAsync(d_out, 0, (size_t)N_TOK * D_IN * 4, stream);
  }

  cvt_all<<<1024, 256, 0, stream>>>(X, W1, W3, W2, U1, U2, U3,
                                    Xbf, Xa0, W13b, W2b, U1b, U2b, U3b);
  tpose_bf<<<dim3(D_IN / 32, N_TOK / 32), 256, 0, stream>>>(X, XaT0);

  u16* XaC[2]  = {Xa0, Xa1};
  u16* XaTC[2] = {XaT0, XaT1};

  for (int n = 0; n < 2; ++n) {
    const int cur = n & 1, nxt = cur ^ 1;
    const size_t uoff = (size_t)n * D_IN * D_IN;
    // h = tanh(Xa @ W1^T), k = Xa @ W3^T  (fused; TOTAL=8 -> 3-buf pipeline)
    gemm128<5, 1, D_IN><<<dim3(2, 32), 256, 0, stream>>>(
        XaC[cur], D_IN, 0, W13b, D_IN,
        nullptr, 0, 0, nullptr, 0, nullptr, 0, 0, nullptr, 0,
        nullptr, hb, kb, 64, 64);
    // q = h @ W2^T  (TOTAL=1 -> 24 KB LDS)
    gemm128<2, 1, D_ATTN><<<dim3(1, 32), 256, 0, stream>>>(
        hb, D_ATTN, 0, W2b, D_ATTN,
        nullptr, 0, 0, nullptr, 0, nullptr, 0, 0, nullptr, 0,
        nullptr, qb, nullptr, D_ATTN, 0);
    // S = q @ k^T -> bf16  (2048 blocks; TOTAL=1 -> high occupancy)
    gemm128<2, 1, D_ATTN><<<dim3(64, 32), 256, 0, stream>>>(
        qb, D_ATTN, 0, kb, D_ATTN,
        nullptr, 0, 0, nullptr, 0, nullptr, 0, 0, nullptr, 0,
        nullptr, S16, nullptr, N_TOK, 0);
    // softmax + top-p -> A
    nucleus_block<<<N_TOK / 2, 256, 0, stream>>>(S16, Abuf, apitch);
    // Xa_new = A @ Xa
    if (splitK) {
      gemm128<6, 1, N_TOK / 4><<<dim3(8, 32, 4), 256, 0, stream>>>(
          Abuf, apitch, 0, XaTC[cur], N_TOK,
          nullptr, 0, 0, nullptr, 0, nullptr, 0, 0, nullptr, 0,
          Zp, nullptr, nullptr, D_IN, N_TOK * D_IN);
      if (n == 0)
        pvfix<true><<<dim3(D_IN / 64, N_TOK / 64), 256, 0, stream>>>(
            Zp, XaC[nxt], XaTC[nxt]);
      else
        pvfix<false><<<dim3(D_IN / 64, N_TOK / 64), 256, 0, stream>>>(
            Zp, XaC[nxt], nullptr);
    } else {
      gemm128<4, 1, N_TOK><<<dim3(8, 32), 256, 0, stream>>>(
          Abuf, apitch, 0, XaTC[cur], N_TOK,
          nullptr, 0, 0, nullptr, 0, nullptr, 0, 0, nullptr, 0,
          nullptr, XaC[nxt], XaTC[nxt], D_IN, N_TOK);
    }
    // Z += Xf@U1^T + Xb@U2^T + Xa_new@U3^T
    if (projSplit) {
      gemm128<3, 3, D_IN / 2><<<dim3(8, 32, 2), 256, 0, stream>>>(
          Xbf, D_IN, -(n + 1), U1b + uoff, D_IN,
          Xbf, D_IN,  (n + 1), U2b + uoff, D_IN,
          XaC[nxt], D_IN, 0,   U3b + uoff, D_IN,
          Zq, nullptr, nullptr, D_IN, N_TOK * D_IN);
    } else {
      gemm128<3, 3, D_IN><<<dim3(8, 32), 256, 0, stream>>>(
          Xbf, D_IN, -(n + 1), U1b + uoff, D_IN,
          Xbf, D_IN,  (n + 1), U2b + uoff, D_IN,
          XaC[nxt], D_IN, 0,   U3b + uoff, D_IN,
          Z, nullptr, nullptr, D_IN, 0);
    }
  }

  // y = X + Z(0)+Z(1) ; LayerNorm -> d_out
  if (projSplit) {
    ln_kernel<<<N_TOK / 2, 256, 0, stream>>>(
        X, Zq, Zq + (size_t)N_TOK * D_IN, (float*)d_out, gamma, beta);
  } else {
    ln_kernel<<<N_TOK / 2, 256, 0, stream>>>(
        X, Z, nullptr, (float*)d_out, gamma, beta);
  }
}

// Round 18
// 336.054 us; speedup vs baseline: 1.0723x; 1.0031x over previous
//
#include <hip/hip_runtime.h>
#include <hip/hip_bf16.h>
#include <math.h>

typedef short bf16x8 __attribute__((ext_vector_type(8)));
typedef float f32x4 __attribute__((ext_vector_type(4)));
typedef unsigned short u16;
typedef unsigned long long u64;

#define N_TOK  4096
#define D_IN   512
#define D_ATTN 64
#define NBI    1024
#define CAPW   128
#define TOPP   0.9f
#define LN_EPS 1e-5f
#define AMAXV  (N_TOK - 1)
#define FLTMAX 3.402823466e38f
#define MSCALE 524288.0f   /* 2^19 fixed-point mass scale */

__device__ __forceinline__ u16 f2bf(float f) {
  unsigned int u = __float_as_uint(f);
  return (u16)((u + 0x7FFFu + ((u >> 16) & 1u)) >> 16);
}

__device__ __forceinline__ float bf2f(u16 v) {
  return __uint_as_float(((unsigned)v) << 16);
}

__device__ __forceinline__ unsigned mfix(float e) {
  return (unsigned)(e * MSCALE + 0.5f);
}

__device__ __forceinline__ void gload16(const u16* g, u16* l) {
  __builtin_amdgcn_global_load_lds(
      (const __attribute__((address_space(1))) unsigned int*)g,
      (__attribute__((address_space(3))) unsigned int*)l, 16, 0, 0);
}

// ---------------------------------------------------------------------------
// gemm128 (R13/R14 proven config + BN template param): BM=128, BK=64.
// DB = min(TOTAL,3) LDS buffers; counted-vmcnt pipeline for long-K.
// EPI: 0 f32; 1 tanh->bf16; 2 bf16; 3 f32 += (z-partial); 4 bf16 dual;
//      5 split col<64 tanh->Cb / col>=64 CbT; 6 f32 -> Cf + z*ldct
// ---------------------------------------------------------------------------
template<int EPI, int NSEG, int KSEG, int BN = 64>
__global__ __launch_bounds__(256)
void gemm128(const u16* __restrict__ A0, int lda0, int sh0, const u16* __restrict__ B0, int ldb0,
             const u16* __restrict__ A1, int lda1, int sh1, const u16* __restrict__ B1, int ldb1,
             const u16* __restrict__ A2, int lda2, int sh2, const u16* __restrict__ B2, int ldb2,
             float* __restrict__ Cf, u16* __restrict__ Cb, u16* __restrict__ CbT,
             int ldc, int ldct)
{
  constexpr int NF = BN / 32;
  constexpr int IPSEG = KSEG >> 6;
  constexpr int TOTAL = NSEG * IPSEG;
  constexpr int DB = (TOTAL < 3) ? TOTAL : 3;

  __shared__ u16 sA[DB][128 * 64];
  __shared__ u16 sB[DB][BN * 64];

  const int tid  = threadIdx.x;
  const int wave = tid >> 6;
  const int lane = tid & 63;
  const int l15  = lane & 15;
  const int l4   = lane >> 4;
  const int brow = blockIdx.y << 7;
  const int bcol = blockIdx.x * BN;
  const int kz   = blockIdx.z * KSEG;
  const int wr64 = (wave >> 1) << 6;
  const int wcol = (wave & 1) * (BN >> 1);

  auto stage = [&](int buf, int it) {
    int seg = (NSEG == 1) ? 0 : (it / IPSEG);
    int kk  = (NSEG == 1) ? (it << 6) : ((it % IPSEG) << 6);
    const u16 *Ab, *Bb; int la, lb, sh;
    if (seg == 0)      { Ab = A0; la = lda0; sh = sh0; Bb = B0; lb = ldb0; }
    else if (seg == 1) { Ab = A1; la = lda1; sh = sh1; Bb = B1; lb = ldb1; }
    else               { Ab = A2; la = lda2; sh = sh2; Bb = B2; lb = ldb2; }
    kk += kz;
#pragma unroll
    for (int q = 0; q < 4; ++q) {              // A tile 128x64
      int idx = q * 256 + tid;
      int row = idx >> 3;
      int chunk = (idx & 7) ^ (row & 7);
      int r = brow + row + sh;
      r = (r < 0) ? 0 : ((r > AMAXV) ? AMAXV : r);
      gload16(Ab + (size_t)r * la + kk + chunk * 8, &sA[buf][idx * 8]);
    }
#pragma unroll
    for (int q = 0; q < BN / 32; ++q) {        // B tile BNx64
      int idx = q * 256 + tid;
      int row = idx >> 3;
      int chunk = (idx & 7) ^ (row & 7);
      gload16(Bb + (size_t)(bcol + row) * lb + kk + chunk * 8, &sB[buf][idx * 8]);
    }
  };

  f32x4 acc[4][NF];
#pragma unroll
  for (int m = 0; m < 4; ++m)
#pragma unroll
    for (int n = 0; n < NF; ++n) {
      acc[m][n][0] = 0.f; acc[m][n][1] = 0.f; acc[m][n][2] = 0.f; acc[m][n][3] = 0.f;
    }

  stage(0, 0);
  if (TOTAL > 1) stage(1 % DB, 1);

  for (int i = 0; i < TOTAL; ++i) {
    if (i + 1 < TOTAL) asm volatile("s_waitcnt vmcnt(6)" ::: "memory");
    else               asm volatile("s_waitcnt vmcnt(0)" ::: "memory");
    __builtin_amdgcn_s_barrier();
    if (i + 2 < TOTAL) stage((i + 2) % DB, i + 2);
    const int c = i % DB;
#pragma unroll
    for (int ks = 0; ks < 2; ++ks) {
      bf16x8 af[4], bfr[NF];
#pragma unroll
      for (int m = 0; m < 4; ++m) {
        int ar = wr64 + m * 16 + l15;
        af[m] = *(const bf16x8*)&sA[c][ar * 64 + (((ks << 2) + l4) ^ (ar & 7)) * 8];
      }
#pragma unroll
      for (int n = 0; n < NF; ++n) {
        int br = wcol + n * 16 + l15;
        bfr[n] = *(const bf16x8*)&sB[c][br * 64 + (((ks << 2) + l4) ^ (br & 7)) * 8];
      }
#pragma unroll
      for (int m = 0; m < 4; ++m)
#pragma unroll
        for (int n = 0; n < NF; ++n)
          acc[m][n] = __builtin_amdgcn_mfma_f32_16x16x32_bf16(af[m], bfr[n], acc[m][n], 0, 0, 0);
    }
  }

  float* Cfz = (EPI == 6 || EPI == 3) ? (Cf + (size_t)blockIdx.z * (size_t)ldct) : Cf;
#pragma unroll
  for (int m = 0; m < 4; ++m)
#pragma unroll
    for (int n = 0; n < NF; ++n)
#pragma unroll
      for (int r = 0; r < 4; ++r) {
        const int row = brow + wr64 + m * 16 + l4 * 4 + r;
        const int col = bcol + wcol + n * 16 + l15;
        const float v = acc[m][n][r];
        if (EPI == 0) Cf[(size_t)row * ldc + col] = v;
        if (EPI == 1) Cb[(size_t)row * ldc + col] = f2bf(tanhf(v));
        if (EPI == 2) Cb[(size_t)row * ldc + col] = f2bf(v);
        if (EPI == 3) Cfz[(size_t)row * ldc + col] += v;
        if (EPI == 4) {
          u16 hv = f2bf(v);
          Cb [(size_t)row * ldc  + col] = hv;
          CbT[(size_t)col * ldct + row] = hv;
        }
        if (EPI == 5) {
          if (col < 64) Cb [(size_t)row * 64 + col]        = f2bf(tanhf(v));
          else          CbT[(size_t)row * 64 + (col - 64)] = f2bf(v);
        }
        if (EPI == 6) Cfz[(size_t)row * ldc + col] = v;
      }
}

// ---------------------------------------------------------------------------
// pvfix: Xa = bf16(sum of 4 split-K partials); XaT = Xa^T only if WRT.
// ---------------------------------------------------------------------------
template<bool WRT>
__global__ __launch_bounds__(256)
void pvfix(const float* __restrict__ Zp, u16* __restrict__ Xa, u16* __restrict__ XaT)
{
  const size_t st = (size_t)N_TOK * D_IN;
  __shared__ u16 tile[64][65];
  const int bx = blockIdx.x, by = blockIdx.y;
  const int t = threadIdx.x;
  const int tx = t & 15, ty = t >> 4;
#pragma unroll
  for (int i = 0; i < 4; ++i) {
    int r = by * 64 + ty + 16 * i;
    int c = bx * 64 + tx * 4;
    size_t idx = (size_t)r * D_IN + c;
    float4 a = *(const float4*)&Zp[idx];
    float4 b = *(const float4*)&Zp[idx + st];
    float4 d = *(const float4*)&Zp[idx + 2 * st];
    float4 e = *(const float4*)&Zp[idx + 3 * st];
    u16 q0 = f2bf(a.x + b.x + d.x + e.x), q1 = f2bf(a.y + b.y + d.y + e.y);
    u16 q2 = f2bf(a.z + b.z + d.z + e.z), q3 = f2bf(a.w + b.w + d.w + e.w);
    *(ushort4*)&Xa[idx] = make_ushort4(q0, q1, q2, q3);
    if (WRT) {
      tile[ty + 16 * i][tx * 4 + 0] = q0;
      tile[ty + 16 * i][tx * 4 + 1] = q1;
      tile[ty + 16 * i][tx * 4 + 2] = q2;
      tile[ty + 16 * i][tx * 4 + 3] = q3;
    }
  }
  if (WRT) {
    __syncthreads();
#pragma unroll
    for (int i = 0; i < 4; ++i) {
      int cc = ty + 16 * i;
      int rq = tx * 4;
      u16 o0 = tile[rq + 0][cc], o1 = tile[rq + 1][cc];
      u16 o2 = tile[rq + 2][cc], o3 = tile[rq + 3][cc];
      *(ushort4*)&XaT[(size_t)(bx * 64 + cc) * N_TOK + by * 64 + rq] =
          make_ushort4(o0, o1, o2, o3);
    }
  }
}

// ---------------------------------------------------------------------------
// Block-per-row nucleus (R14/R17 proven version — VGPR 64, 8 waves/SIMD).
// ---------------------------------------------------------------------------
__global__ __launch_bounds__(256)
void nucleus_block(const u16* __restrict__ S, u16* __restrict__ A, int apitch)
{
  const int t = threadIdx.x;
  const int wv = t >> 6, ln = t & 63;

  __shared__ unsigned hist[4][NBI];        // 16 KB
  __shared__ float ge[CAPW];
  __shared__ int   gcol[CAPW];
  __shared__ unsigned gm[CAPW];
  __shared__ unsigned char kf[CAPW];
  __shared__ float sMin[4], sMax[4], sDen[4];
  __shared__ int   sCnt[4], sS[4];
  __shared__ unsigned sScan[4];
  __shared__ unsigned s_Ab;
  __shared__ int   s_cnt;

  for (int rr = 0; rr < 2; ++rr) {
    const int row = blockIdx.x + rr * (N_TOK / 2);
    const u16* srow = S + (size_t)row * N_TOK;
    u16* arow = A + (size_t)row * apitch;

    __syncthreads();

    float evf[16];
    float lmax = -FLTMAX, lmin = FLTMAX;
#pragma unroll
    for (int q = 0; q < 4; ++q) {
      ushort4 v = ((const ushort4*)srow)[q * 256 + t];
      float e0 = bf2f(v.x), e1 = bf2f(v.y), e2 = bf2f(v.z), e3 = bf2f(v.w);
      evf[4*q+0] = e0; evf[4*q+1] = e1; evf[4*q+2] = e2; evf[4*q+3] = e3;
      lmax = fmaxf(lmax, fmaxf(fmaxf(e0, e1), fmaxf(e2, e3)));
      lmin = fminf(lmin, fminf(fminf(e0, e1), fminf(e2, e3)));
    }
#pragma unroll
    for (int o = 32; o; o >>= 1) {
      lmax = fmaxf(lmax, __shfl_xor(lmax, o));
      lmin = fminf(lmin, __shfl_xor(lmin, o));
    }
    if (ln == 0) { sMax[wv] = lmax; sMin[wv] = lmin; }
    __syncthreads();
    const float smax = fmaxf(fmaxf(sMax[0], sMax[1]), fmaxf(sMax[2], sMax[3]));
    const float smin = fminf(fminf(sMin[0], sMin[1]), fminf(sMin[2], sMin[3]));

#pragma unroll
    for (int j = 0; j < 16; ++j) evf[j] = __expf(evf[j] - smax);

    unsigned keepM = 0, cand = 0xFFFFu;
    unsigned Agt = 0, T = 0;
    bool haveT = false;
    float lo = __expf(smin - smax);
    float width = fmaxf(1.0f - lo, 1e-30f);

    for (int lev = 0; lev < 12; ++lev) {
      __syncthreads();
      {
        uint4 z; z.x = 0; z.y = 0; z.z = 0; z.w = 0;
        ((uint4*)hist[0])[t] = z; ((uint4*)hist[1])[t] = z;
        ((uint4*)hist[2])[t] = z; ((uint4*)hist[3])[t] = z;
      }
      int myCnt = __popc(cand);
      float cmin = FLTMAX, cmax = -FLTMAX;
#pragma unroll
      for (int j = 0; j < 16; ++j)
        if ((cand >> j) & 1) { float e = evf[j]; cmin = fminf(cmin, e); cmax = fmaxf(cmax, e); }
      int ct = myCnt;
#pragma unroll
      for (int o = 32; o; o >>= 1) {
        ct   += __shfl_xor(ct, o);
        cmin  = fminf(cmin, __shfl_xor(cmin, o));
        cmax  = fmaxf(cmax, __shfl_xor(cmax, o));
      }
      if (ln == 0) { sCnt[wv] = ct; sMin[wv] = cmin; sMax[wv] = cmax; }
      __syncthreads();
      const int tot = sCnt[0] + sCnt[1] + sCnt[2] + sCnt[3];
      cmin = fminf(fminf(sMin[0], sMin[1]), fminf(sMin[2], sMin[3]));
      cmax = fmaxf(fmaxf(sMax[0], sMax[1]), fmaxf(sMax[2], sMax[3]));

      if (tot == 0) break;

      if (haveT && (cmin == cmax || lev == 11)) {
        const float v = cmax;
        const unsigned mv = mfix(v);
        int r;
        if (T <= Agt) r = 0;
        else if (mv == 0) r = tot;
        else { unsigned need = T - Agt; r = (int)((need + mv - 1) / mv); if (r > tot) r = tot; }
        int cq[4], excl[4];
#pragma unroll
        for (int q = 0; q < 4; ++q) {
          cq[q] = __popc((cand >> (4 * q)) & 0xF);
          int sc = cq[q];
#pragma unroll
          for (int o = 1; o < 64; o <<= 1) { int u = __shfl_up(sc, o); if (ln >= o) sc += u; }
          excl[q] = sc - cq[q];
          if (ln == 63) hist[wv][NBI - 4 + q] = (unsigned)(excl[q] + cq[q]);
        }
        __syncthreads();
        int qtot[4], woffq[4];
#pragma unroll
        for (int q = 0; q < 4; ++q) {
          unsigned w0 = hist[0][NBI - 4 + q], w1 = hist[1][NBI - 4 + q],
                   w2 = hist[2][NBI - 4 + q], w3 = hist[3][NBI - 4 + q];
          woffq[q] = (wv > 0 ? (int)w0 : 0) + (wv > 1 ? (int)w1 : 0) + (wv > 2 ? (int)w2 : 0);
          qtot[q]  = (int)(w0 + w1 + w2 + w3);
        }
        int qbase = 0;
#pragma unroll
        for (int q = 0; q < 4; ++q) {
          int seen = 0;
#pragma unroll
          for (int jj = 0; jj < 4; ++jj) {
            int j = 4 * q + jj;
            if ((cand >> j) & 1) {
              int rank = qbase + woffq[q] + excl[q] + seen;
              if (rank < r) keepM |= 1u << j;
              ++seen;
            }
          }
          qbase += qtot[q];
        }
        break;
      }

      if (haveT && tot <= CAPW) {
        if (t == 0) s_cnt = 0;
        __syncthreads();
#pragma unroll
        for (int j = 0; j < 16; ++j) {
          if ((cand >> j) & 1) {
            int i = atomicAdd(&s_cnt, 1);
            ge[i] = evf[j];
            gm[i] = mfix(evf[j]);
            gcol[i] = ((j >> 2) << 10) + (t << 2) + (j & 3);
          }
        }
        __syncthreads();
        const int cnt = s_cnt;
        if (t < cnt) {
          float ei = ge[t]; int ci = gcol[t];
          unsigned m = Agt;
          for (int u = 0; u < cnt; ++u) {
            float el = ge[u];
            if (el > ei || (el == ei && gcol[u] < ci)) m += gm[u];
          }
          kf[t] = (m < T) ? 1 : 0;
        }
        __syncthreads();
        for (int u = 0; u < cnt; ++u) {
          int c = gcol[u];
          if (((c >> 2) & 255) == t && kf[u])
            keepM |= 1u << (((c >> 10) << 2) | (c & 3));
        }
        break;
      }

      const float scale = (float)NBI / width;
      __syncthreads();
      unsigned* Hw = hist[wv];
#pragma unroll
      for (int j = 0; j < 16; ++j) {
        if ((cand >> j) & 1) {
          float e = evf[j];
          int b = (int)((e - lo) * scale);
          b = (b < 0) ? 0 : ((b > NBI - 1) ? NBI - 1 : b);
          atomicAdd(&Hw[b], mfix(e));
        }
      }
      __syncthreads();
      unsigned hv[4];
      {
        uint4 a0 = ((const uint4*)hist[0])[t];
        uint4 a1 = ((const uint4*)hist[1])[t];
        uint4 a2 = ((const uint4*)hist[2])[t];
        uint4 a3 = ((const uint4*)hist[3])[t];
        hv[0] = a0.x + a1.x + a2.x + a3.x;
        hv[1] = a0.y + a1.y + a2.y + a3.y;
        hv[2] = a0.z + a1.z + a2.z + a3.z;
        hv[3] = a0.w + a1.w + a2.w + a3.w;
      }
      unsigned sl = (hv[0] + hv[1]) + (hv[2] + hv[3]);
      unsigned pv = sl;
#pragma unroll
      for (int o = 1; o < 64; o <<= 1) { unsigned u = __shfl_up(pv, o); if (ln >= o) pv += u; }
      if (ln == 63) sScan[wv] = pv;
      __syncthreads();
      const unsigned woff = (wv > 0 ? sScan[0] : 0u) + (wv > 1 ? sScan[1] : 0u) + (wv > 2 ? sScan[2] : 0u);
      const unsigned CM   = sScan[0] + sScan[1] + sScan[2] + sScan[3];
      if (!haveT) {
        T = (unsigned)((9ULL * (unsigned long long)CM) / 10ULL);
        haveT = true;
      }
      const unsigned incl = pv + woff;
      unsigned Arun = Agt + (CM - incl);
      int lb = -1; unsigned Ab = 0;
#pragma unroll
      for (int j = 3; j >= 0; --j) {
        unsigned bm = hv[j];
        if (Arun < T && Arun + bm >= T) { lb = j; Ab = Arun; }
        Arun += bm;
      }
      int bl = (lb >= 0) ? ((t << 2) | lb) : -1;
      int s = bl;
#pragma unroll
      for (int o = 32; o; o >>= 1) s = max(s, __shfl_xor(s, o));
      if (ln == 0) sS[wv] = s;
      __syncthreads();
      s = max(max(sS[0], sS[1]), max(sS[2], sS[3]));
      if (s < 0) { keepM |= cand; break; }
      if (bl == s) s_Ab = Ab;
      __syncthreads();
      const unsigned Abnd = s_Ab;
      unsigned nk = 0, nc = 0;
#pragma unroll
      for (int j = 0; j < 16; ++j) {
        if ((cand >> j) & 1) {
          float e = evf[j];
          int b = (int)((e - lo) * scale);
          b = (b < 0) ? 0 : ((b > NBI - 1) ? NBI - 1 : b);
          if (b > s) nk |= 1u << j;
          else if (b == s) nc |= 1u << j;
        }
      }
      keepM |= nk;
      cand = nc;
      Agt = Abnd;
      width = fmaxf(width * (1.0f / NBI), 1e-37f);
      lo = lo + (float)s * width;
    }

    // ---- exact denominator from keep mask (float)
    float dl = 0.f;
#pragma unroll
    for (int j = 0; j < 16; ++j)
      if ((keepM >> j) & 1) dl += evf[j];
#pragma unroll
    for (int o = 32; o; o >>= 1) dl += __shfl_xor(dl, o);
    if (ln == 0) sDen[wv] = dl;
    __syncthreads();
    float den = sDen[0] + sDen[1] + sDen[2] + sDen[3];
    if (den <= 0.f) den = 1.f;
    const float invd = 1.0f / den;

#pragma unroll
    for (int q = 0; q < 4; ++q) {
      u16 rr4[4];
#pragma unroll
      for (int j = 0; j < 4; ++j) {
        int b = 4 * q + j;
        float val = ((keepM >> b) & 1) ? evf[b] * invd : 0.f;
        rr4[j] = f2bf(val);
      }
      ((ushort4*)arow)[q * 256 + t] = make_ushort4(rr4[0], rr4[1], rr4[2], rr4[3]);
    }
  }
}

// ---------------------------------------------------------------------------
// cvt_all: single dest per segment (Xa0 dual-write dropped — Xbf is read
// directly as step-0's Xa input; Xa0 is only ever a pvfix output now).
// ---------------------------------------------------------------------------
__global__ void cvt_all(const float* __restrict__ X,  const float* __restrict__ W1,
                        const float* __restrict__ W3, const float* __restrict__ W2,
                        const float* __restrict__ U1, const float* __restrict__ U2,
                        const float* __restrict__ U3,
                        u16* __restrict__ Xbf,
                        u16* __restrict__ W13b, u16* __restrict__ W2b,
                        u16* __restrict__ U1b, u16* __restrict__ U2b, u16* __restrict__ U3b)
{
  const int NX = 524288, NW = 8192, NW2 = 1024, NU = 131072;
  const int TOT = NX + 2 * NW + NW2 + 3 * NU;
  const int stride = gridDim.x * 256;
  for (int i = blockIdx.x * 256 + threadIdx.x; i < TOT; i += stride) {
    const float* s; u16* d; int rel;
    if (i < NX)                       { s = X;  d = Xbf;  rel = i; }
    else if (i < NX + NW)             { s = W1; d = W13b; rel = i - NX; }
    else if (i < NX + 2*NW)           { s = W3; d = W13b + (size_t)4*NW; rel = i - NX - NW; }
    else if (i < NX + 2*NW + NW2)     { s = W2; d = W2b;  rel = i - NX - 2*NW; }
    else if (i < NX + 2*NW + NW2 + NU){ s = U1; d = U1b;  rel = i - NX - 2*NW - NW2; }
    else if (i < NX + 2*NW + NW2+2*NU){ s = U2; d = U2b;  rel = i - NX - 2*NW - NW2 - NU; }
    else                              { s = U3; d = U3b;  rel = i - NX - 2*NW - NW2 - 2*NU; }
    float4 v = ((const float4*)s)[rel];
    ushort4 o;
    o.x = f2bf(v.x); o.y = f2bf(v.y); o.z = f2bf(v.z); o.w = f2bf(v.w);
    ((ushort4*)d)[rel] = o;
  }
}

__global__ __launch_bounds__(256)
void tpose_bf(const float* __restrict__ X, u16* __restrict__ XT)
{
  __shared__ u16 tile[32][33];
  const int bc = blockIdx.x * 32;
  const int br = blockIdx.y * 32;
  const int tx = threadIdx.x & 31, ty = threadIdx.x >> 5;
#pragma unroll
  for (int i = 0; i < 32; i += 8)
    tile[ty + i][tx] = f2bf(X[(size_t)(br + ty + i) * D_IN + bc + tx]);
  __syncthreads();
#pragma unroll
  for (int i = 0; i < 32; i += 8)
    XT[(size_t)(bc + ty + i) * N_TOK + br + tx] = tile[tx][ty + i];
}

// y = X + Z0 (+ Z1); LayerNorm -> OUT.  Z1 may be null.
__global__ __launch_bounds__(256)
void ln_kernel(const float* __restrict__ X, const float* __restrict__ Z0,
               const float* __restrict__ Z1, float* __restrict__ OUT,
               const float* __restrict__ gamma, const float* __restrict__ beta)
{
  const int tid = threadIdx.x;
  __shared__ float red[4];
  __shared__ float s_mu, s_var;
  for (int rr = 0; rr < 2; ++rr) {
    const int row = blockIdx.x + rr * (N_TOK / 2);
    const size_t base = (size_t)row * D_IN;
    __syncthreads();
    float y0 = X[base + tid] + Z0[base + tid];
    float y1 = X[base + tid + 256] + Z0[base + tid + 256];
    if (Z1) { y0 += Z1[base + tid]; y1 += Z1[base + tid + 256]; }
    float s = y0 + y1;
    for (int o = 32; o; o >>= 1) s += __shfl_xor(s, o);
    if ((tid & 63) == 0) red[tid >> 6] = s;
    __syncthreads();
    if (tid == 0) s_mu = (red[0] + red[1] + red[2] + red[3]) * (1.f / D_IN);
    __syncthreads();
    const float mu = s_mu;
    float d0 = y0 - mu, d1 = y1 - mu;
    float v = d0 * d0 + d1 * d1;
    for (int o = 32; o; o >>= 1) v += __shfl_xor(v, o);
    if ((tid & 63) == 0) red[tid >> 6] = v;
    __syncthreads();
    if (tid == 0) s_var = (red[0] + red[1] + red[2] + red[3]) * (1.f / D_IN);
    __syncthreads();
    const float rs = rsqrtf(s_var + LN_EPS);
    OUT[base + tid]       = d0 * rs * gamma[tid]       + beta[tid];
    OUT[base + tid + 256] = d1 * rs * gamma[tid + 256] + beta[tid + 256];
  }
}

// ---------------------------------------------------------------------------
extern "C" void kernel_launch(void* const* d_in, const int* in_sizes, int n_in,
                              void* d_out, int out_size, void* d_ws, size_t ws_size,
                              hipStream_t stream)
{
  const float* X     = (const float*)d_in[0];
  const float* W1    = (const float*)d_in[1];
  const float* W2    = (const float*)d_in[2];
  const float* W3    = (const float*)d_in[3];
  const float* U1    = (const float*)d_in[4];
  const float* U2    = (const float*)d_in[5];
  const float* U3    = (const float*)d_in[6];
  const float* gamma = (const float*)d_in[7];
  const float* beta  = (const float*)d_in[8];

  char* w = (char*)d_ws;
  u16* S16    = (u16*)w;              w += (size_t)N_TOK * N_TOK * 2;   // 32 MB
  u16* Xbf    = (u16*)w;              w += (size_t)N_TOK * D_IN * 2;
  u16* Xa0    = (u16*)w;              w += (size_t)N_TOK * D_IN * 2;
  u16* Xa1    = (u16*)w;              w += (size_t)N_TOK * D_IN * 2;
  u16* XaT0   = (u16*)w;              w += (size_t)D_IN * N_TOK * 2;
  u16* XaT1   = (u16*)w;              w += (size_t)D_IN * N_TOK * 2;
  u16* hb     = (u16*)w;              w += (size_t)N_TOK * D_ATTN * 2;
  u16* qb     = (u16*)w;              w += (size_t)N_TOK * D_ATTN * 2;
  u16* kb     = (u16*)w;              w += (size_t)N_TOK * D_ATTN * 2;
  u16* W13b   = (u16*)w;              w += (size_t)2 * D_ATTN * D_IN * 2;
  u16* W2b    = (u16*)w;              w += (size_t)D_ATTN * D_ATTN * 2;
  u16* U1b    = (u16*)w;              w += (size_t)2 * D_IN * D_IN * 2;
  u16* U2b    = (u16*)w;              w += (size_t)2 * D_IN * D_IN * 2;
  u16* U3b    = (u16*)w;              w += (size_t)2 * D_IN * D_IN * 2;

  size_t used = (size_t)(w - (char*)d_ws);
  u16* Abuf;
  int  apitch = N_TOK;
  if (ws_size >= used + (size_t)N_TOK * N_TOK * 2) {
    Abuf = (u16*)w;
    w += (size_t)N_TOK * N_TOK * 2;
  } else {
    Abuf = S16;                        // in-place fallback (bounded algo; safe)
  }
  used = (size_t)(w - (char*)d_ws);
  float* Zp = nullptr;
  const bool splitK = (ws_size >= used + 4 * (size_t)N_TOK * D_IN * 4);
  if (splitK) { Zp = (float*)w; w += 4 * (size_t)N_TOK * D_IN * 4; }
  used = (size_t)(w - (char*)d_ws);
  float* Zq = nullptr;                 // proj split-K partials (2x 8MB)
  const bool projSplit = (ws_size >= used + 2 * (size_t)N_TOK * D_IN * 4);
  if (projSplit) { Zq = (float*)w; w += 2 * (size_t)N_TOK * D_IN * 4; }

  float* Z = (float*)d_out;

  if (projSplit) {
    hipMemsetAsync(Zq, 0, 2 * (size_t)N_TOK * D_IN * 4, stream);
  } else {
    hipMemsetAsync(d_out, 0, (size_t)N_TOK * D_IN * 4, stream);
  }

  cvt_all<<<1024, 256, 0, stream>>>(X, W1, W3, W2, U1, U2, U3,
                                    Xbf, W13b, W2b, U1b, U2b, U3b);
  tpose_bf<<<dim3(D_IN / 32, N_TOK / 32), 256, 0, stream>>>(X, XaT0);

  // step-0 reads Xbf (== bf16(X)); pvfix outputs go Xa1 (step0) / Xa0 (step1)
  const u16* XaIn[2]  = {Xbf, Xa1};
  u16*       XaOut[2] = {Xa1, Xa0};
  u16* XaTC[2] = {XaT0, XaT1};

  for (int n = 0; n < 2; ++n) {
    const int cur = n & 1;
    const size_t uoff = (size_t)n * D_IN * D_IN;
    // h = tanh(Xa @ W1^T), k = Xa @ W3^T  (fused; TOTAL=8 -> 3-buf pipeline)
    gemm128<5, 1, D_IN><<<dim3(2, 32), 256, 0, stream>>>(
        XaIn[n], D_IN, 0, W13b, D_IN,
        nullptr, 0, 0, nullptr, 0, nullptr, 0, 0, nullptr, 0,
        nullptr, hb, kb, 64, 64);
    // q = h @ W2^T  (TOTAL=1 -> 24 KB LDS)
    gemm128<2, 1, D_ATTN><<<dim3(1, 32), 256, 0, stream>>>(
        hb, D_ATTN, 0, W2b, D_ATTN,
        nullptr, 0, 0, nullptr, 0, nullptr, 0, 0, nullptr, 0,
        nullptr, qb, nullptr, D_ATTN, 0);
    // S = q @ k^T -> bf16  (BN=128 -> 1024 blocks; A-tile staged once)
    gemm128<2, 1, D_ATTN, 128><<<dim3(32, 32), 256, 0, stream>>>(
        qb, D_ATTN, 0, kb, D_ATTN,
        nullptr, 0, 0, nullptr, 0, nullptr, 0, 0, nullptr, 0,
        nullptr, S16, nullptr, N_TOK, 0);
    // softmax + top-p -> A
    nucleus_block<<<N_TOK / 2, 256, 0, stream>>>(S16, Abuf, apitch);
    // Xa_new = A @ Xa
    if (splitK) {
      gemm128<6, 1, N_TOK / 4><<<dim3(8, 32, 4), 256, 0, stream>>>(
          Abuf, apitch, 0, XaTC[cur], N_TOK,
          nullptr, 0, 0, nullptr, 0, nullptr, 0, 0, nullptr, 0,
          Zp, nullptr, nullptr, D_IN, N_TOK * D_IN);
      if (n == 0)
        pvfix<true><<<dim3(D_IN / 64, N_TOK / 64), 256, 0, stream>>>(
            Zp, XaOut[n], XaTC[cur ^ 1]);
      else
        pvfix<false><<<dim3(D_IN / 64, N_TOK / 64), 256, 0, stream>>>(
            Zp, XaOut[n], nullptr);
    } else {
      gemm128<4, 1, N_TOK><<<dim3(8, 32), 256, 0, stream>>>(
          Abuf, apitch, 0, XaTC[cur], N_TOK,
          nullptr, 0, 0, nullptr, 0, nullptr, 0, 0, nullptr, 0,
          nullptr, XaOut[n], XaTC[cur ^ 1], D_IN, N_TOK);
    }
    // Z += Xf@U1^T + Xb@U2^T + Xa_new@U3^T
    if (projSplit) {
      gemm128<3, 3, D_IN / 2><<<dim3(8, 32, 2), 256, 0, stream>>>(
          Xbf, D_IN, -(n + 1), U1b + uoff, D_IN,
          Xbf, D_IN,  (n + 1), U2b + uoff, D_IN,
          XaOut[n], D_IN, 0,   U3b + uoff, D_IN,
          Zq, nullptr, nullptr, D_IN, N_TOK * D_IN);
    } else {
      gemm128<3, 3, D_IN><<<dim3(8, 32), 256, 0, stream>>>(
          Xbf, D_IN, -(n + 1), U1b + uoff, D_IN,
          Xbf, D_IN,  (n + 1), U2b + uoff, D_IN,
          XaOut[n], D_IN, 0,   U3b + uoff, D_IN,
          Z, nullptr, nullptr, D_IN, 0);
    }
  }

  // y = X + Z(0)+Z(1) ; LayerNorm -> d_out
  if (projSplit) {
    ln_kernel<<<N_TOK / 2, 256, 0, stream>>>(
        X, Zq, Zq + (size_t)N_TOK * D_IN, (float*)d_out, gamma, beta);
  } else {
    ln_kernel<<<N_TOK / 2, 256, 0, stream>>>(
        X, Z, nullptr, (float*)d_out, gamma, beta);
  }
}